// Round 1
// baseline (1848.402 us; speedup 1.0000x reference)
//
#include <hip/hip_runtime.h>
#include <math.h>

#define TB 2048
#define NB 4
#define NH 16
#define HD 64
#define DM 1024
#define MROWS (NB * TB) /* 8192 */

// ---------------------------------------------------------------------------
// Shared SGEMM body: C[M=rows][N] = A[M][K] * W[K][N] (+bias), 128x128 tile,
// BK=16, 256 threads, 8x8 per thread (rows/cols split 4+4 at stride 64).
// ---------------------------------------------------------------------------
__device__ __forceinline__ void gemm_body(const float* __restrict__ A,
                                          const float* __restrict__ W,
                                          const float* __restrict__ bias,
                                          float* __restrict__ C,
                                          int bm, int bn, int K, int N)
{
    __shared__ float As[16][132];
    __shared__ float Bs[16][132];
    const int tid = threadIdx.x;
    const int tx = tid & 15, ty = tid >> 4;

    float acc[8][8];
#pragma unroll
    for (int i = 0; i < 8; ++i)
#pragma unroll
        for (int j = 0; j < 8; ++j) acc[i][j] = 0.f;

    for (int k0 = 0; k0 < K; k0 += 16) {
        __syncthreads();
#pragma unroll
        for (int t = 0; t < 2; ++t) {
            int f = tid + t * 256;
            int ar = f >> 2, ac = (f & 3) << 2;
            float4 av = *(const float4*)&A[(size_t)(bm + ar) * K + (k0 + ac)];
            As[ac + 0][ar] = av.x;
            As[ac + 1][ar] = av.y;
            As[ac + 2][ar] = av.z;
            As[ac + 3][ar] = av.w;
            int br = f >> 5, bc = (f & 31) << 2;
            *(float4*)&Bs[br][bc] =
                *(const float4*)&W[(size_t)(k0 + br) * N + (bn + bc)];
        }
        __syncthreads();
#pragma unroll
        for (int kk = 0; kk < 16; ++kk) {
            float4 a0 = *(const float4*)&As[kk][ty * 4];
            float4 a1 = *(const float4*)&As[kk][64 + ty * 4];
            float4 b0 = *(const float4*)&Bs[kk][tx * 4];
            float4 b1 = *(const float4*)&Bs[kk][64 + tx * 4];
            float av[8] = {a0.x, a0.y, a0.z, a0.w, a1.x, a1.y, a1.z, a1.w};
            float bv[8] = {b0.x, b0.y, b0.z, b0.w, b1.x, b1.y, b1.z, b1.w};
#pragma unroll
            for (int i = 0; i < 8; ++i)
#pragma unroll
                for (int j = 0; j < 8; ++j)
                    acc[i][j] = fmaf(av[i], bv[j], acc[i][j]);
        }
    }

#pragma unroll
    for (int i = 0; i < 8; ++i) {
        int r = bm + ((i < 4) ? (ty * 4 + i) : (64 + ty * 4 + (i - 4)));
#pragma unroll
        for (int half = 0; half < 2; ++half) {
            int c = bn + half * 64 + tx * 4;
            float4 v;
            v.x = acc[i][half * 4 + 0];
            v.y = acc[i][half * 4 + 1];
            v.z = acc[i][half * 4 + 2];
            v.w = acc[i][half * 4 + 3];
            if (bias) {
                v.x += bias[c + 0];
                v.y += bias[c + 1];
                v.z += bias[c + 2];
                v.w += bias[c + 3];
            }
            *(float4*)&C[(size_t)r * N + c] = v;
        }
    }
}

__global__ __launch_bounds__(256) void qkv_kernel(const float* __restrict__ x,
                                                  const float* __restrict__ Wq,
                                                  const float* __restrict__ Wk,
                                                  const float* __restrict__ Wv,
                                                  float* __restrict__ ws)
{
    const int z = blockIdx.z;
    const float* W = (z == 0) ? Wq : (z == 1) ? Wk : Wv;
    float* C = ws + (size_t)z * MROWS * DM;
    gemm_body(x, W, nullptr, C, blockIdx.x * 128, blockIdx.y * 128, DM, DM);
}

__global__ __launch_bounds__(256) void proj_kernel(const float* __restrict__ ctx,
                                                   const float* __restrict__ Wo,
                                                   const float* __restrict__ bo,
                                                   float* __restrict__ out)
{
    gemm_body(ctx, Wo, bo, out, blockIdx.x * 128, blockIdx.y * 128, DM, DM);
}

// ---------------------------------------------------------------------------
// Flash attention: one block per (b, h, 64-row q-tile). fp32 on vector ALU.
// S cols per thread: c = tx + 16*j (conflict-free K reads + shfl row-reduce).
// P is written back into the K LDS buffer (aliased). O cols: c = tx*4 + j.
// ---------------------------------------------------------------------------
__global__ __launch_bounds__(256) void attn_kernel(const float* __restrict__ Qg,
                                                   const float* __restrict__ Kg,
                                                   const float* __restrict__ Vg,
                                                   float* __restrict__ ctx)
{
    __shared__ float Qs[64][68];
    __shared__ float Ks[64][68];  // reused to hold P after S-compute
    __shared__ float Vs[64][68];

    const int tid = threadIdx.x;
    const int tx = tid & 15, ty = tid >> 4;
    const int qi = blockIdx.x, h = blockIdx.y, b = blockIdx.z;
    const int q0 = qi * 64;
    const size_t base = ((size_t)b * TB) * DM + (size_t)h * HD;

    // Q tile -> LDS
#pragma unroll
    for (int t = 0; t < 4; ++t) {
        int f = tid + t * 256;
        int r = f >> 4, dd = (f & 15) << 2;
        *(float4*)&Qs[r][dd] = *(const float4*)&Qg[base + (size_t)(q0 + r) * DM + dd];
    }

    float m[4], l[4], o[4][4];
#pragma unroll
    for (int i = 0; i < 4; ++i) {
        m[i] = -INFINITY;
        l[i] = 0.f;
#pragma unroll
        for (int j = 0; j < 4; ++j) o[i][j] = 0.f;
    }

    for (int kt = 0; kt <= qi; ++kt) {
        const int k0 = kt * 64;
        __syncthreads();  // protect Ks/Vs from previous iteration's readers
#pragma unroll
        for (int t = 0; t < 4; ++t) {
            int f = tid + t * 256;
            int r = f >> 4, dd = (f & 15) << 2;
            *(float4*)&Ks[r][dd] =
                *(const float4*)&Kg[base + (size_t)(k0 + r) * DM + dd];
            *(float4*)&Vs[r][dd] =
                *(const float4*)&Vg[base + (size_t)(k0 + r) * DM + dd];
        }
        __syncthreads();

        // S = Q * K^T  (4 rows x 4 cols per thread, cols c = tx + 16*j)
        float s[4][4];
#pragma unroll
        for (int i = 0; i < 4; ++i)
#pragma unroll
            for (int j = 0; j < 4; ++j) s[i][j] = 0.f;

#pragma unroll
        for (int d0 = 0; d0 < 64; d0 += 4) {
            float4 qv[4], kv[4];
#pragma unroll
            for (int i = 0; i < 4; ++i) qv[i] = *(const float4*)&Qs[ty * 4 + i][d0];
#pragma unroll
            for (int j = 0; j < 4; ++j) kv[j] = *(const float4*)&Ks[tx + 16 * j][d0];
#pragma unroll
            for (int i = 0; i < 4; ++i)
#pragma unroll
                for (int j = 0; j < 4; ++j) {
                    s[i][j] = fmaf(qv[i].x, kv[j].x, s[i][j]);
                    s[i][j] = fmaf(qv[i].y, kv[j].y, s[i][j]);
                    s[i][j] = fmaf(qv[i].z, kv[j].z, s[i][j]);
                    s[i][j] = fmaf(qv[i].w, kv[j].w, s[i][j]);
                }
        }

        // scale (1/sqrt(64)) + causal mask (diagonal tile only)
#pragma unroll
        for (int i = 0; i < 4; ++i)
#pragma unroll
            for (int j = 0; j < 4; ++j) {
                s[i][j] *= 0.125f;
                if (kt == qi && (tx + 16 * j) > (ty * 4 + i)) s[i][j] = -INFINITY;
            }

        // online softmax update (row-reduce across the 16 tx lanes)
        float p[4][4];
#pragma unroll
        for (int i = 0; i < 4; ++i) {
            float pm = fmaxf(fmaxf(s[i][0], s[i][1]), fmaxf(s[i][2], s[i][3]));
            pm = fmaxf(pm, __shfl_xor(pm, 1));
            pm = fmaxf(pm, __shfl_xor(pm, 2));
            pm = fmaxf(pm, __shfl_xor(pm, 4));
            pm = fmaxf(pm, __shfl_xor(pm, 8));
            float mn = fmaxf(m[i], pm);
            float sc = __expf(m[i] - mn);
            float rs = 0.f;
#pragma unroll
            for (int j = 0; j < 4; ++j) {
                p[i][j] = __expf(s[i][j] - mn);
                rs += p[i][j];
            }
            rs += __shfl_xor(rs, 1);
            rs += __shfl_xor(rs, 2);
            rs += __shfl_xor(rs, 4);
            rs += __shfl_xor(rs, 8);
            l[i] = l[i] * sc + rs;
            m[i] = mn;
#pragma unroll
            for (int j = 0; j < 4; ++j) o[i][j] *= sc;
        }

        __syncthreads();  // everyone done reading Ks as K
        // write P into the Ks buffer at true column positions
#pragma unroll
        for (int i = 0; i < 4; ++i)
#pragma unroll
            for (int j = 0; j < 4; ++j)
                Ks[ty * 4 + i][tx + 16 * j] = p[i][j];
        __syncthreads();

        // O += P * V  (output cols d = tx*4 + j, contiguous float4)
#pragma unroll
        for (int k4 = 0; k4 < 64; k4 += 4) {
            float pr[4][4];
#pragma unroll
            for (int i = 0; i < 4; ++i) {
                float4 pv = *(const float4*)&Ks[ty * 4 + i][k4];
                pr[i][0] = pv.x; pr[i][1] = pv.y; pr[i][2] = pv.z; pr[i][3] = pv.w;
            }
#pragma unroll
            for (int kk = 0; kk < 4; ++kk) {
                float4 vv = *(const float4*)&Vs[k4 + kk][tx * 4];
#pragma unroll
                for (int i = 0; i < 4; ++i) {
                    o[i][0] = fmaf(pr[i][kk], vv.x, o[i][0]);
                    o[i][1] = fmaf(pr[i][kk], vv.y, o[i][1]);
                    o[i][2] = fmaf(pr[i][kk], vv.z, o[i][2]);
                    o[i][3] = fmaf(pr[i][kk], vv.w, o[i][3]);
                }
            }
        }
    }

    // normalize + store ctx[b, q, h, :]
#pragma unroll
    for (int i = 0; i < 4; ++i) {
        float inv = 1.f / l[i];
        float4 v;
        v.x = o[i][0] * inv;
        v.y = o[i][1] * inv;
        v.z = o[i][2] * inv;
        v.w = o[i][3] * inv;
        *(float4*)&ctx[base + (size_t)(q0 + ty * 4 + i) * DM + tx * 4] = v;
    }
}

// ---------------------------------------------------------------------------
extern "C" void kernel_launch(void* const* d_in, const int* in_sizes, int n_in,
                              void* d_out, int out_size, void* d_ws, size_t ws_size,
                              hipStream_t stream)
{
    const float* x  = (const float*)d_in[0];
    const float* Wq = (const float*)d_in[1];
    const float* Wk = (const float*)d_in[2];
    const float* Wv = (const float*)d_in[3];
    const float* Wo = (const float*)d_in[4];
    const float* bo = (const float*)d_in[5];
    float* out = (float*)d_out;

    float* ws  = (float*)d_ws;
    float* Q   = ws;
    float* K   = ws + (size_t)1 * MROWS * DM;
    float* V   = ws + (size_t)2 * MROWS * DM;
    float* ctx = ws + (size_t)3 * MROWS * DM;

    // Q, K, V projections (fused launch; z picks the weight)
    qkv_kernel<<<dim3(MROWS / 128, DM / 128, 3), 256, 0, stream>>>(x, Wq, Wk, Wv, ws);

    // causal flash attention
    attn_kernel<<<dim3(TB / 64, NH, NB), 256, 0, stream>>>(Q, K, V, ctx);

    // output projection + bias
    proj_kernel<<<dim3(MROWS / 128, DM / 128, 1), 256, 0, stream>>>(ctx, Wo, bo, out);
}

// Round 2
// 680.289 us; speedup vs baseline: 2.7171x; 2.7171x over previous
//
#include <hip/hip_runtime.h>
#include <math.h>

#define TB 2048
#define NB 4
#define NH 16
#define HD 64
#define DM 1024
#define MROWS (NB * TB) /* 8192 */

typedef unsigned short u16;
typedef __attribute__((ext_vector_type(8))) short bf16x8;
typedef __attribute__((ext_vector_type(8))) u16 u16x8;
typedef __attribute__((ext_vector_type(4))) u16 u16x4;
typedef __attribute__((ext_vector_type(4))) float f32x4;

// elems per one [8192][1024] bf16 half-array
#define SZE ((size_t)MROWS * DM) /* 8,388,608 */
#define WSZE ((size_t)DM * DM)   /* 1,048,576 */

// ---------------------------------------------------------------------------
// bf16 helpers (RNE)
// ---------------------------------------------------------------------------
__device__ __forceinline__ u16 f2bf(float f) {
    union { float f; unsigned u; } c; c.f = f;
    unsigned u = c.u + 0x7FFFu + ((c.u >> 16) & 1u);
    return (u16)(u >> 16);
}
__device__ __forceinline__ float bf2f(u16 h) {
    union { unsigned u; float f; } c; c.u = ((unsigned)h) << 16;
    return c.f;
}

__device__ __forceinline__ void gload16(const u16* g, u16* l) {
    __builtin_amdgcn_global_load_lds(
        (const __attribute__((address_space(1))) void*)g,
        (__attribute__((address_space(3))) void*)l, 16, 0, 0);
}

// ---------------------------------------------------------------------------
// convert x -> (xh, xl)   8 elems/thread, exact cover of 8.39M elems
// ---------------------------------------------------------------------------
__global__ __launch_bounds__(256) void convert_x(const float* __restrict__ x,
                                                 u16* __restrict__ xh,
                                                 u16* __restrict__ xl)
{
    size_t i = ((size_t)blockIdx.x * 256 + threadIdx.x) * 8;
    float4 a = *(const float4*)(x + i);
    float4 b = *(const float4*)(x + i + 4);
    float v[8] = {a.x, a.y, a.z, a.w, b.x, b.y, b.z, b.w};
    u16x8 hi, lo;
#pragma unroll
    for (int j = 0; j < 8; ++j) {
        u16 h = f2bf(v[j]);
        hi[j] = h;
        lo[j] = f2bf(v[j] - bf2f(h));
    }
    *(u16x8*)(xh + i) = hi;
    *(u16x8*)(xl + i) = lo;
}

// ---------------------------------------------------------------------------
// convert + transpose weights: W[K][N] fp32 -> Wt_h/Wt_l [N][K] bf16
// z = blockIdx.z selects {Wq,Wk,Wv,Wo}; out pair at wt + z*2*WSZE
// ---------------------------------------------------------------------------
__global__ __launch_bounds__(256) void convert_wt(const float* __restrict__ Wq,
                                                  const float* __restrict__ Wk,
                                                  const float* __restrict__ Wv,
                                                  const float* __restrict__ Wo,
                                                  u16* __restrict__ wt)
{
    const int z = blockIdx.z;
    const float* W = (z == 0) ? Wq : (z == 1) ? Wk : (z == 2) ? Wv : Wo;
    u16* dh = wt + (size_t)z * 2 * WSZE;
    u16* dl = dh + WSZE;
    __shared__ float tile[64][65];
    const int tid = threadIdx.x;
    const int k0 = blockIdx.x * 64, n0 = blockIdx.y * 64;
#pragma unroll
    for (int i = 0; i < 4; ++i) {
        int c = i * 256 + tid, r = c >> 4, c4 = (c & 15) << 2;
        *(float4*)&tile[r][c4] = *(const float4*)&W[(size_t)(k0 + r) * DM + n0 + c4];
    }
    __syncthreads();
#pragma unroll
    for (int i = 0; i < 4; ++i) {
        int c = i * 256 + tid, n = c >> 4, k4 = (c & 15) << 2;
        u16x4 hi, lo;
#pragma unroll
        for (int j = 0; j < 4; ++j) {
            float v = tile[k4 + j][n];
            u16 h = f2bf(v);
            hi[j] = h;
            lo[j] = f2bf(v - bf2f(h));
        }
        *(u16x4*)(dh + (size_t)(n0 + n) * DM + k0 + k4) = hi;
        *(u16x4*)(dl + (size_t)(n0 + n) * DM + k0 + k4) = lo;
    }
}

// ---------------------------------------------------------------------------
// V transpose: Vh/Vl [B,H,T,D] -> Vth/Vtl [B,H,D,T]
// ---------------------------------------------------------------------------
__global__ __launch_bounds__(256) void vtrans(const u16* __restrict__ Vh,
                                              const u16* __restrict__ Vl,
                                              u16* __restrict__ Vth,
                                              u16* __restrict__ Vtl)
{
    __shared__ u16 th[64][72];
    __shared__ u16 tl[64][72];
    const int tid = threadIdx.x;
    const int t0 = blockIdx.x * 64;
    const size_t bh = blockIdx.y;
#pragma unroll
    for (int i = 0; i < 2; ++i) {
        int c = i * 256 + tid, r = c >> 3, d8 = (c & 7) << 3;
        u16x8 vh = *(const u16x8*)(Vh + (bh * TB + t0 + r) * HD + d8);
        u16x8 vl = *(const u16x8*)(Vl + (bh * TB + t0 + r) * HD + d8);
        *(u16x8*)&th[r][d8] = vh;
        *(u16x8*)&tl[r][d8] = vl;
    }
    __syncthreads();
#pragma unroll
    for (int i = 0; i < 2; ++i) {
        int c = i * 256 + tid, d = c >> 3, t8 = (c & 7) << 3;
        u16x8 vh, vl;
#pragma unroll
        for (int j = 0; j < 8; ++j) {
            vh[j] = th[t8 + j][d];
            vl[j] = tl[t8 + j][d];
        }
        *(u16x8*)(Vth + (bh * HD + d) * TB + t0 + t8) = vh;
        *(u16x8*)(Vtl + (bh * HD + d) * TB + t0 + t8) = vl;
    }
}

// ---------------------------------------------------------------------------
// split-bf16 NT GEMM core: C[128][128] tile of A[M][1024] * Bt[N][1024]^T
// 4 waves 2x2, per wave 64x64 = 4x4 frags of 16x16x32 mfma, 3 mfma per frag
// per k-step (hh + hl + lh). LDS tiles [128][32] u16 with src-side swizzle
// (slot ^= (row>>1)&3), linear global_load_lds dest.
// ---------------------------------------------------------------------------
__device__ __forceinline__ void gemm_nt_128(const u16* __restrict__ A_h,
                                            const u16* __restrict__ A_l,
                                            const u16* __restrict__ B_h,
                                            const u16* __restrict__ B_l,
                                            int bm, int bn, u16* lds,
                                            f32x4 acc[4][4])
{
    const int tid = threadIdx.x, lane = tid & 63;
    const int wid = tid >> 6, wm = wid >> 1, wn = wid & 1;
    const int lr = lane & 15, g = lane >> 4;
    u16* sAh = lds;
    u16* sAl = lds + 4096;
    u16* sBh = lds + 8192;
    u16* sBl = lds + 12288;

#pragma unroll
    for (int i = 0; i < 4; ++i)
#pragma unroll
        for (int j = 0; j < 4; ++j) acc[i][j] = (f32x4)0.f;

    for (int k0 = 0; k0 < DM; k0 += 32) {
        __syncthreads();
#pragma unroll
        for (int i = 0; i < 2; ++i) {
            int c = i * 256 + tid, r = c >> 2, db = c & 3;
            int src = db ^ ((r >> 1) & 3);
            size_t ga = (size_t)(bm + r) * DM + k0 + src * 8;
            size_t gb = (size_t)(bn + r) * DM + k0 + src * 8;
            gload16(A_h + ga, sAh + c * 8);
            gload16(A_l + ga, sAl + c * 8);
            gload16(B_h + gb, sBh + c * 8);
            gload16(B_l + gb, sBl + c * 8);
        }
        __syncthreads();

        bf16x8 ah[4], al[4], bh[4], bl[4];
#pragma unroll
        for (int f = 0; f < 4; ++f) {
            int ra = wm * 64 + f * 16 + lr;
            int oa = ra * 32 + ((g ^ ((ra >> 1) & 3)) << 3);
            ah[f] = *(const bf16x8*)(sAh + oa);
            al[f] = *(const bf16x8*)(sAl + oa);
            int rb = wn * 64 + f * 16 + lr;
            int ob = rb * 32 + ((g ^ ((rb >> 1) & 3)) << 3);
            bh[f] = *(const bf16x8*)(sBh + ob);
            bl[f] = *(const bf16x8*)(sBl + ob);
        }
#pragma unroll
        for (int fi = 0; fi < 4; ++fi)
#pragma unroll
            for (int fj = 0; fj < 4; ++fj) {
                acc[fi][fj] = __builtin_amdgcn_mfma_f32_16x16x32_bf16(
                    ah[fi], bh[fj], acc[fi][fj], 0, 0, 0);
                acc[fi][fj] = __builtin_amdgcn_mfma_f32_16x16x32_bf16(
                    ah[fi], bl[fj], acc[fi][fj], 0, 0, 0);
                acc[fi][fj] = __builtin_amdgcn_mfma_f32_16x16x32_bf16(
                    al[fi], bh[fj], acc[fi][fj], 0, 0, 0);
            }
    }
}

// QKV projections: z selects weight pair and output pair; output written
// split-bf16 in [B,H,T,D] layout.
__global__ __launch_bounds__(256) void qkv_gemm(const u16* __restrict__ xh,
                                                const u16* __restrict__ xl,
                                                const u16* __restrict__ wt,
                                                u16* __restrict__ qkvb)
{
    __shared__ u16 lds[16384];
    const int z = blockIdx.z;
    const u16* Bh = wt + (size_t)z * 2 * WSZE;
    const u16* Bl = Bh + WSZE;
    u16* outh = qkvb + (size_t)z * 2 * SZE;
    u16* outl = outh + SZE;
    const int bm = blockIdx.x * 128, bn = blockIdx.y * 128;

    f32x4 acc[4][4];
    gemm_nt_128(xh, xl, Bh, Bl, bm, bn, lds, acc);

    const int lane = threadIdx.x & 63, wid = threadIdx.x >> 6;
    const int wm = wid >> 1, wn = wid & 1;
    const int lr = lane & 15, g = lane >> 4;
#pragma unroll
    for (int fi = 0; fi < 4; ++fi)
#pragma unroll
        for (int fj = 0; fj < 4; ++fj)
#pragma unroll
            for (int reg = 0; reg < 4; ++reg) {
                int m = bm + wm * 64 + fi * 16 + g * 4 + reg;
                int n = bn + wn * 64 + fj * 16 + lr;
                int b = m >> 11, t = m & (TB - 1);
                int h = n >> 6, d = n & 63;
                float v = acc[fi][fj][reg];
                u16 hi = f2bf(v);
                u16 lo = f2bf(v - bf2f(hi));
                size_t o = ((size_t)(b * NH + h) * TB + t) * HD + d;
                outh[o] = hi;
                outl[o] = lo;
            }
}

// Output projection + bias -> fp32 out
__global__ __launch_bounds__(256) void proj_gemm(const u16* __restrict__ ch,
                                                 const u16* __restrict__ cl,
                                                 const u16* __restrict__ Bh,
                                                 const u16* __restrict__ Bl,
                                                 const float* __restrict__ bo,
                                                 float* __restrict__ out)
{
    __shared__ u16 lds[16384];
    const int bm = blockIdx.x * 128, bn = blockIdx.y * 128;
    f32x4 acc[4][4];
    gemm_nt_128(ch, cl, Bh, Bl, bm, bn, lds, acc);

    const int lane = threadIdx.x & 63, wid = threadIdx.x >> 6;
    const int wm = wid >> 1, wn = wid & 1;
    const int lr = lane & 15, g = lane >> 4;
#pragma unroll
    for (int fi = 0; fi < 4; ++fi)
#pragma unroll
        for (int fj = 0; fj < 4; ++fj) {
            int n = bn + wn * 64 + fj * 16 + lr;
            float bias = bo[n];
#pragma unroll
            for (int reg = 0; reg < 4; ++reg) {
                int m = bm + wm * 64 + fi * 16 + g * 4 + reg;
                out[(size_t)m * DM + n] = acc[fi][fj][reg] + bias;
            }
        }
}

// ---------------------------------------------------------------------------
// Flash attention, split-bf16 MFMA. One block per (qtile64, h, b); 4 waves,
// wave w owns q-rows w*16..w*16+15. K/V tiles of 64 keys staged split-bf16
// in LDS ([64][64] u16, slot ^= row&7 swizzle via pre-swizzled global src).
// P bounced through wave-private LDS rows (no extra barriers needed).
// ---------------------------------------------------------------------------
__global__ __launch_bounds__(256) void attn_kernel(const u16* __restrict__ Qh,
                                                   const u16* __restrict__ Ql,
                                                   const u16* __restrict__ Kh,
                                                   const u16* __restrict__ Kl,
                                                   const u16* __restrict__ Vth,
                                                   const u16* __restrict__ Vtl,
                                                   u16* __restrict__ ctxh,
                                                   u16* __restrict__ ctxl)
{
    __shared__ u16 lds[8 * 4096]; // Qh Ql Kh Kl Vh Vl Ph Pl, each [64][64]
    u16* sQh = lds;
    u16* sQl = lds + 4096;
    u16* sKh = lds + 8192;
    u16* sKl = lds + 12288;
    u16* sVh = lds + 16384;
    u16* sVl = lds + 20480;
    u16* sPh = lds + 24576;
    u16* sPl = lds + 28672;

    const int tid = threadIdx.x, lane = tid & 63, wid = tid >> 6;
    const int lr = lane & 15, g = lane >> 4;
    const int qi = blockIdx.x, h = blockIdx.y, b = blockIdx.z;
    const int q0 = qi * 64;
    const size_t bh = (size_t)(b * NH + h);

    // stage Q tile (once)
#pragma unroll
    for (int i = 0; i < 2; ++i) {
        int c = i * 256 + tid, r = c >> 3, sl = c & 7;
        int src = sl ^ (r & 7);
        size_t gq = (bh * TB + q0 + r) * HD + src * 8;
        gload16(Qh + gq, sQh + c * 8);
        gload16(Ql + gq, sQl + c * 8);
    }

    f32x4 o[4];
    float mrun[4], lrun[4];
#pragma unroll
    for (int i = 0; i < 4; ++i) {
        o[i] = (f32x4)0.f;
        mrun[i] = -INFINITY;
        lrun[i] = 0.f;
    }

    for (int kt = 0; kt <= qi; ++kt) {
        __syncthreads();
#pragma unroll
        for (int i = 0; i < 2; ++i) {
            int c = i * 256 + tid, r = c >> 3, sl = c & 7;
            int src = sl ^ (r & 7);
            size_t gk = (bh * TB + kt * 64 + r) * HD + src * 8;
            gload16(Kh + gk, sKh + c * 8);
            gload16(Kl + gk, sKl + c * 8);
            size_t gv = (bh * HD + r) * TB + kt * 64 + src * 8;
            gload16(Vth + gv, sVh + c * 8);
            gload16(Vtl + gv, sVl + c * 8);
        }
        __syncthreads();

        // ---- S = Q K^T (k-dim = d = 64, 2 mfma-ksteps, split x3) ----
        bf16x8 qah[2], qal[2];
#pragma unroll
        for (int ks = 0; ks < 2; ++ks) {
            int r = wid * 16 + lr;
            int off = r * 64 + (((ks * 4 + g) ^ (r & 7)) << 3);
            qah[ks] = *(const bf16x8*)(sQh + off);
            qal[ks] = *(const bf16x8*)(sQl + off);
        }
        f32x4 s[4];
#pragma unroll
        for (int fj = 0; fj < 4; ++fj) {
            s[fj] = (f32x4)0.f;
#pragma unroll
            for (int ks = 0; ks < 2; ++ks) {
                int rb = fj * 16 + lr;
                int ob = rb * 64 + (((ks * 4 + g) ^ (rb & 7)) << 3);
                bf16x8 kbh = *(const bf16x8*)(sKh + ob);
                bf16x8 kbl = *(const bf16x8*)(sKl + ob);
                s[fj] = __builtin_amdgcn_mfma_f32_16x16x32_bf16(qah[ks], kbh, s[fj], 0, 0, 0);
                s[fj] = __builtin_amdgcn_mfma_f32_16x16x32_bf16(qah[ks], kbl, s[fj], 0, 0, 0);
                s[fj] = __builtin_amdgcn_mfma_f32_16x16x32_bf16(qal[ks], kbh, s[fj], 0, 0, 0);
            }
        }

        // ---- online softmax (rows r = wid*16 + g*4 + reg) ----
        const bool diag = (kt == qi);
#pragma unroll
        for (int reg = 0; reg < 4; ++reg) {
            int qg = wid * 16 + g * 4 + reg; // row within 64-tile
            float v4[4];
            float mloc = -INFINITY;
#pragma unroll
            for (int fj = 0; fj < 4; ++fj) {
                float sv = s[fj][reg] * 0.125f;
                int key = fj * 16 + lr;
                if (diag && key > qg) sv = -INFINITY;
                v4[fj] = sv;
                mloc = fmaxf(mloc, sv);
            }
            mloc = fmaxf(mloc, __shfl_xor(mloc, 1));
            mloc = fmaxf(mloc, __shfl_xor(mloc, 2));
            mloc = fmaxf(mloc, __shfl_xor(mloc, 4));
            mloc = fmaxf(mloc, __shfl_xor(mloc, 8));
            float mn = fmaxf(mrun[reg], mloc);
            float scx = __expf(mrun[reg] - mn);
            float rs = 0.f;
            float p[4];
#pragma unroll
            for (int fj = 0; fj < 4; ++fj) {
                p[fj] = __expf(v4[fj] - mn);
                rs += p[fj];
            }
            rs += __shfl_xor(rs, 1);
            rs += __shfl_xor(rs, 2);
            rs += __shfl_xor(rs, 4);
            rs += __shfl_xor(rs, 8);
            lrun[reg] = lrun[reg] * scx + rs;
            mrun[reg] = mn;
#pragma unroll
            for (int fd = 0; fd < 4; ++fd) o[fd][reg] *= scx;
            // write P (wave-private rows; swizzled like all tiles)
#pragma unroll
            for (int fj = 0; fj < 4; ++fj) {
                int cc = fj * 16 + lr;
                int addr = qg * 64 + (((cc >> 3) ^ (qg & 7)) << 3) + (cc & 7);
                u16 hi = f2bf(p[fj]);
                sPh[addr] = hi;
                sPl[addr] = f2bf(p[fj] - bf2f(hi));
            }
        }

        // ---- O += P V (k-dim = keys = 64; B-operand = Vt rows d) ----
        bf16x8 pah[2], pal[2];
#pragma unroll
        for (int ks = 0; ks < 2; ++ks) {
            int r = wid * 16 + lr;
            int off = r * 64 + (((ks * 4 + g) ^ (r & 7)) << 3);
            pah[ks] = *(const bf16x8*)(sPh + off);
            pal[ks] = *(const bf16x8*)(sPl + off);
        }
#pragma unroll
        for (int fd = 0; fd < 4; ++fd)
#pragma unroll
            for (int ks = 0; ks < 2; ++ks) {
                int rb = fd * 16 + lr;
                int ob = rb * 64 + (((ks * 4 + g) ^ (rb & 7)) << 3);
                bf16x8 vbh = *(const bf16x8*)(sVh + ob);
                bf16x8 vbl = *(const bf16x8*)(sVl + ob);
                o[fd] = __builtin_amdgcn_mfma_f32_16x16x32_bf16(pah[ks], vbh, o[fd], 0, 0, 0);
                o[fd] = __builtin_amdgcn_mfma_f32_16x16x32_bf16(pah[ks], vbl, o[fd], 0, 0, 0);
                o[fd] = __builtin_amdgcn_mfma_f32_16x16x32_bf16(pal[ks], vbh, o[fd], 0, 0, 0);
            }
    }

    // ---- epilogue: ctx[b, t, h*64+d] split-bf16 ----
#pragma unroll
    for (int reg = 0; reg < 4; ++reg) {
        float inv = 1.f / lrun[reg];
        int t = q0 + wid * 16 + g * 4 + reg;
#pragma unroll
        for (int fd = 0; fd < 4; ++fd) {
            int d = fd * 16 + lr;
            float v = o[fd][reg] * inv;
            u16 hi = f2bf(v);
            u16 lo = f2bf(v - bf2f(hi));
            size_t oi = ((size_t)b * TB + t) * DM + h * HD + d;
            ctxh[oi] = hi;
            ctxl[oi] = lo;
        }
    }
}

// ---------------------------------------------------------------------------
extern "C" void kernel_launch(void* const* d_in, const int* in_sizes, int n_in,
                              void* d_out, int out_size, void* d_ws, size_t ws_size,
                              hipStream_t stream)
{
    const float* x  = (const float*)d_in[0];
    const float* Wq = (const float*)d_in[1];
    const float* Wk = (const float*)d_in[2];
    const float* Wv = (const float*)d_in[3];
    const float* Wo = (const float*)d_in[4];
    const float* bo = (const float*)d_in[5];
    float* out = (float*)d_out;

    u16* w = (u16*)d_ws;
    // region A (aliased): xh/xl then Vth/Vtl
    u16* xh  = w;
    u16* xl  = w + SZE;
    u16* vth = w;          // valid after qkv_gemm is done with x
    u16* vtl = w + SZE;
    // region B: 8 transposed weight halves
    u16* wt  = w + 2 * SZE;
    // region C: Q/K/V split halves; ctx aliases V-normal after vtrans
    u16* qkvb = w + 3 * SZE;
    u16* qh = qkvb;
    u16* ql = qkvb + SZE;
    u16* kh = qkvb + 2 * SZE;
    u16* kl = qkvb + 3 * SZE;
    u16* vh = qkvb + 4 * SZE;
    u16* vl = qkvb + 5 * SZE;
    u16* ctxh = vh;        // V-normal dead after vtrans
    u16* ctxl = vl;

    convert_x<<<dim3(4096), 256, 0, stream>>>(x, xh, xl);
    convert_wt<<<dim3(16, 16, 4), 256, 0, stream>>>(Wq, Wk, Wv, Wo, wt);
    qkv_gemm<<<dim3(MROWS / 128, DM / 128, 3), 256, 0, stream>>>(xh, xl, wt, qkvb);
    vtrans<<<dim3(TB / 64, NB * NH), 256, 0, stream>>>(vh, vl, vth, vtl);
    attn_kernel<<<dim3(TB / 64, NH, NB), 256, 0, stream>>>(qh, ql, kh, kl, vth, vtl,
                                                           ctxh, ctxl);
    proj_gemm<<<dim3(MROWS / 128, DM / 128), 256, 0, stream>>>(
        ctxh, ctxl, wt + 3 * 2 * WSZE, wt + 3 * 2 * WSZE + WSZE, bo, out);
}

// Round 3
// 529.231 us; speedup vs baseline: 3.4926x; 1.2854x over previous
//
#include <hip/hip_runtime.h>
#include <math.h>

#define TB 2048
#define NB 4
#define NH 16
#define HD 64
#define DM 1024
#define MROWS (NB * TB) /* 8192 */
#define QBLK 128

typedef unsigned short u16;
typedef __attribute__((ext_vector_type(8))) short bf16x8;
typedef __attribute__((ext_vector_type(8))) u16 u16x8;
typedef __attribute__((ext_vector_type(4))) u16 u16x4;
typedef __attribute__((ext_vector_type(4))) float f32x4;

#define SZE ((size_t)MROWS * DM) /* 8,388,608 elems */
#define WSZE ((size_t)DM * DM)   /* 1,048,576 elems */

// ---------------------------------------------------------------------------
// bf16 helpers (RNE)
// ---------------------------------------------------------------------------
__device__ __forceinline__ u16 f2bf(float f) {
    union { float f; unsigned u; } c; c.f = f;
    unsigned u = c.u + 0x7FFFu + ((c.u >> 16) & 1u);
    return (u16)(u >> 16);
}
__device__ __forceinline__ float bf2f(u16 h) {
    union { unsigned u; float f; } c; c.u = ((unsigned)h) << 16;
    return c.f;
}

__device__ __forceinline__ void gload16(const u16* g, u16* l) {
    __builtin_amdgcn_global_load_lds(
        (const __attribute__((address_space(1))) void*)g,
        (__attribute__((address_space(3))) void*)l, 16, 0, 0);
}

// ---------------------------------------------------------------------------
// convert x -> (xh, xl)
// ---------------------------------------------------------------------------
__global__ __launch_bounds__(256) void convert_x(const float* __restrict__ x,
                                                 u16* __restrict__ xh,
                                                 u16* __restrict__ xl)
{
    size_t i = ((size_t)blockIdx.x * 256 + threadIdx.x) * 8;
    float4 a = *(const float4*)(x + i);
    float4 b = *(const float4*)(x + i + 4);
    float v[8] = {a.x, a.y, a.z, a.w, b.x, b.y, b.z, b.w};
    u16x8 hi, lo;
#pragma unroll
    for (int j = 0; j < 8; ++j) {
        u16 h = f2bf(v[j]);
        hi[j] = h;
        lo[j] = f2bf(v[j] - bf2f(h));
    }
    *(u16x8*)(xh + i) = hi;
    *(u16x8*)(xl + i) = lo;
}

// ---------------------------------------------------------------------------
// convert + transpose weights: W[K][N] fp32 -> Wt_h/Wt_l [N][K] bf16
// ---------------------------------------------------------------------------
__global__ __launch_bounds__(256) void convert_wt(const float* __restrict__ Wq,
                                                  const float* __restrict__ Wk,
                                                  const float* __restrict__ Wv,
                                                  const float* __restrict__ Wo,
                                                  u16* __restrict__ wt)
{
    const int z = blockIdx.z;
    const float* W = (z == 0) ? Wq : (z == 1) ? Wk : (z == 2) ? Wv : Wo;
    u16* dh = wt + (size_t)z * 2 * WSZE;
    u16* dl = dh + WSZE;
    __shared__ float tile[64][65];
    const int tid = threadIdx.x;
    const int k0 = blockIdx.x * 64, n0 = blockIdx.y * 64;
#pragma unroll
    for (int i = 0; i < 4; ++i) {
        int c = i * 256 + tid, r = c >> 4, c4 = (c & 15) << 2;
        *(float4*)&tile[r][c4] = *(const float4*)&W[(size_t)(k0 + r) * DM + n0 + c4];
    }
    __syncthreads();
#pragma unroll
    for (int i = 0; i < 4; ++i) {
        int c = i * 256 + tid, n = c >> 4, k4 = (c & 15) << 2;
        u16x4 hi, lo;
#pragma unroll
        for (int j = 0; j < 4; ++j) {
            float v = tile[k4 + j][n];
            u16 h = f2bf(v);
            hi[j] = h;
            lo[j] = f2bf(v - bf2f(h));
        }
        *(u16x4*)(dh + (size_t)(n0 + n) * DM + k0 + k4) = hi;
        *(u16x4*)(dl + (size_t)(n0 + n) * DM + k0 + k4) = lo;
    }
}

// ---------------------------------------------------------------------------
// split-bf16 NT GEMM core (128x128 tile, BK=32, 4 waves 2x2, 3-MFMA split)
// ---------------------------------------------------------------------------
__device__ __forceinline__ void gemm_nt_128(const u16* __restrict__ A_h,
                                            const u16* __restrict__ A_l,
                                            const u16* __restrict__ B_h,
                                            const u16* __restrict__ B_l,
                                            int bm, int bn, u16* lds,
                                            f32x4 acc[4][4])
{
    const int tid = threadIdx.x, lane = tid & 63;
    const int wid = tid >> 6, wm = wid >> 1, wn = wid & 1;
    const int lr = lane & 15, g = lane >> 4;
    u16* sAh = lds;
    u16* sAl = lds + 4096;
    u16* sBh = lds + 8192;
    u16* sBl = lds + 12288;

#pragma unroll
    for (int i = 0; i < 4; ++i)
#pragma unroll
        for (int j = 0; j < 4; ++j) acc[i][j] = (f32x4)0.f;

    for (int k0 = 0; k0 < DM; k0 += 32) {
        __syncthreads();
#pragma unroll
        for (int i = 0; i < 2; ++i) {
            int c = i * 256 + tid, r = c >> 2, db = c & 3;
            int src = db ^ ((r >> 1) & 3);
            size_t ga = (size_t)(bm + r) * DM + k0 + src * 8;
            size_t gb = (size_t)(bn + r) * DM + k0 + src * 8;
            gload16(A_h + ga, sAh + c * 8);
            gload16(A_l + ga, sAl + c * 8);
            gload16(B_h + gb, sBh + c * 8);
            gload16(B_l + gb, sBl + c * 8);
        }
        __syncthreads();

        bf16x8 ah[4], al[4], bh[4], bl[4];
#pragma unroll
        for (int f = 0; f < 4; ++f) {
            int ra = wm * 64 + f * 16 + lr;
            int oa = ra * 32 + ((g ^ ((ra >> 1) & 3)) << 3);
            ah[f] = *(const bf16x8*)(sAh + oa);
            al[f] = *(const bf16x8*)(sAl + oa);
            int rb = wn * 64 + f * 16 + lr;
            int ob = rb * 32 + ((g ^ ((rb >> 1) & 3)) << 3);
            bh[f] = *(const bf16x8*)(sBh + ob);
            bl[f] = *(const bf16x8*)(sBl + ob);
        }
#pragma unroll
        for (int fi = 0; fi < 4; ++fi)
#pragma unroll
            for (int fj = 0; fj < 4; ++fj) {
                acc[fi][fj] = __builtin_amdgcn_mfma_f32_16x16x32_bf16(
                    ah[fi], bh[fj], acc[fi][fj], 0, 0, 0);
                acc[fi][fj] = __builtin_amdgcn_mfma_f32_16x16x32_bf16(
                    ah[fi], bl[fj], acc[fi][fj], 0, 0, 0);
                acc[fi][fj] = __builtin_amdgcn_mfma_f32_16x16x32_bf16(
                    al[fi], bh[fj], acc[fi][fj], 0, 0, 0);
            }
    }
}

// QKV projections. z=0 -> Q (split, [B,H,T,D]); z=1 -> K (split, [B,H,T,D]);
// z=2 -> V written hi-only, pre-transposed [B,H,D,T] (u16x4 packed stores).
__global__ __launch_bounds__(256) void qkv_gemm(const u16* __restrict__ xh,
                                                const u16* __restrict__ xl,
                                                const u16* __restrict__ wt,
                                                u16* __restrict__ qkvb)
{
    __shared__ u16 lds[16384];
    const int z = blockIdx.z;
    const u16* Bh = wt + (size_t)z * 2 * WSZE;
    const u16* Bl = Bh + WSZE;
    const int bm = blockIdx.x * 128, bn = blockIdx.y * 128;

    f32x4 acc[4][4];
    gemm_nt_128(xh, xl, Bh, Bl, bm, bn, lds, acc);

    const int lane = threadIdx.x & 63, wid = threadIdx.x >> 6;
    const int wm = wid >> 1, wn = wid & 1;
    const int lr = lane & 15, g = lane >> 4;

    if (z < 2) {
        u16* outh = qkvb + (size_t)z * 2 * SZE;
        u16* outl = outh + SZE;
#pragma unroll
        for (int fi = 0; fi < 4; ++fi)
#pragma unroll
            for (int fj = 0; fj < 4; ++fj)
#pragma unroll
                for (int reg = 0; reg < 4; ++reg) {
                    int m = bm + wm * 64 + fi * 16 + g * 4 + reg;
                    int n = bn + wn * 64 + fj * 16 + lr;
                    int b = m >> 11, t = m & (TB - 1);
                    int h = n >> 6, d = n & 63;
                    float v = acc[fi][fj][reg];
                    u16 hi = f2bf(v);
                    u16 lo = f2bf(v - bf2f(hi));
                    size_t o = ((size_t)(b * NH + h) * TB + t) * HD + d;
                    outh[o] = hi;
                    outl[o] = lo;
                }
    } else {
        u16* vth = qkvb + (size_t)4 * SZE;
#pragma unroll
        for (int fi = 0; fi < 4; ++fi)
#pragma unroll
            for (int fj = 0; fj < 4; ++fj) {
                int n = bn + wn * 64 + fj * 16 + lr;
                int h = n >> 6, d = n & 63;
                int m0 = bm + wm * 64 + fi * 16 + g * 4;
                int b = m0 >> 11, t = m0 & (TB - 1);
                u16x4 v4;
#pragma unroll
                for (int reg = 0; reg < 4; ++reg) v4[reg] = f2bf(acc[fi][fj][reg]);
                *(u16x4*)(vth + ((size_t)(b * NH + h) * HD + d) * TB + t) = v4;
            }
    }
}

// Output projection + bias -> fp32 out
__global__ __launch_bounds__(256) void proj_gemm(const u16* __restrict__ ch,
                                                 const u16* __restrict__ cl,
                                                 const u16* __restrict__ Bh,
                                                 const u16* __restrict__ Bl,
                                                 const float* __restrict__ bo,
                                                 float* __restrict__ out)
{
    __shared__ u16 lds[16384];
    const int bm = blockIdx.x * 128, bn = blockIdx.y * 128;
    f32x4 acc[4][4];
    gemm_nt_128(ch, cl, Bh, Bl, bm, bn, lds, acc);

    const int lane = threadIdx.x & 63, wid = threadIdx.x >> 6;
    const int wm = wid >> 1, wn = wid & 1;
    const int lr = lane & 15, g = lane >> 4;
#pragma unroll
    for (int fi = 0; fi < 4; ++fi)
#pragma unroll
        for (int fj = 0; fj < 4; ++fj) {
            int n = bn + wn * 64 + fj * 16 + lr;
            float bias = bo[n];
#pragma unroll
            for (int reg = 0; reg < 4; ++reg) {
                int m = bm + wm * 64 + fi * 16 + g * 4 + reg;
                out[(size_t)m * DM + n] = acc[fi][fj][reg] + bias;
            }
        }
}

// ---------------------------------------------------------------------------
// Flash attention: QBLK=128, 8 waves (512 thr), wave w owns q-rows w*16..+15.
// Q frags hoisted to registers. K split (3-MFMA QK^T); P,V hi-only (1-MFMA PV).
// K/V double-buffered in LDS, 1 barrier/tile (stage t+1 issued before compute
// of t; __syncthreads' vmcnt drain completes it). LDS = 2*24KB + 16KB P = 64KB.
// ---------------------------------------------------------------------------
__device__ __forceinline__ void stage_tile(const u16* __restrict__ Kh,
                                           const u16* __restrict__ Kl,
                                           const u16* __restrict__ Vth,
                                           size_t bh, int k0, u16* dst, int tid)
{
    int r = tid >> 3, sl = tid & 7;
    int src = sl ^ (r & 7);
    size_t gk = (bh * TB + k0 + r) * HD + src * 8;
    gload16(Kh + gk, dst + tid * 8);
    gload16(Kl + gk, dst + 4096 + tid * 8);
    size_t gv = (bh * HD + r) * TB + k0 + src * 8;
    gload16(Vth + gv, dst + 8192 + tid * 8);
}

__global__ __launch_bounds__(512, 4) void attn_kernel(const u16* __restrict__ Qh,
                                                      const u16* __restrict__ Ql,
                                                      const u16* __restrict__ Kh,
                                                      const u16* __restrict__ Kl,
                                                      const u16* __restrict__ Vth,
                                                      u16* __restrict__ ctxh,
                                                      u16* __restrict__ ctxl)
{
    __shared__ u16 lds[32768]; // buf0: Kh/Kl/Vh @0/4096/8192; buf1: +12288; P @24576
    u16* sP = lds + 24576;     // [128][64]

    const int tid = threadIdx.x, lane = tid & 63, wid = tid >> 6;
    const int lr = lane & 15, g = lane >> 4;
    const int qi = (TB / QBLK - 1) - blockIdx.x; // heavy-first
    const int h = blockIdx.y, b = blockIdx.z;
    const int q0 = qi * QBLK;
    const size_t bh = (size_t)(b * NH + h);
    const int nt = 2 * qi + 2;
    const int wq0 = q0 + wid * 16; // wave's first absolute q-row

    // hoisted Q fragments
    bf16x8 qah[2], qal[2];
    {
        size_t rowoff = (bh * TB + wq0 + lr) * HD;
#pragma unroll
        for (int ks = 0; ks < 2; ++ks) {
            qah[ks] = *(const bf16x8*)(Qh + rowoff + ks * 32 + g * 8);
            qal[ks] = *(const bf16x8*)(Ql + rowoff + ks * 32 + g * 8);
        }
    }

    f32x4 o[4];
    float mrun[4], lrun[4];
#pragma unroll
    for (int i = 0; i < 4; ++i) {
        o[i] = (f32x4)0.f;
        mrun[i] = -INFINITY;
        lrun[i] = 0.f;
    }

    stage_tile(Kh, Kl, Vth, bh, 0, lds, tid);

    for (int kt = 0; kt < nt; ++kt) {
        __syncthreads(); // drains vmcnt -> buf[kt&1] ready; prev readers done
        if (kt + 1 < nt)
            stage_tile(Kh, Kl, Vth, bh, (kt + 1) * 64, lds + ((kt + 1) & 1) * 12288, tid);

        const int k0 = kt * 64;
        if (k0 > wq0 + 15) continue; // wave fully masked (only last tile, waves 0-3)

        u16* sK = lds + (kt & 1) * 12288;
        u16* sKlo = sK + 4096;
        u16* sV = sK + 8192;

        // ---- S = Q K^T ----
        f32x4 s[4];
#pragma unroll
        for (int fj = 0; fj < 4; ++fj) {
            s[fj] = (f32x4)0.f;
#pragma unroll
            for (int ks = 0; ks < 2; ++ks) {
                int rb = fj * 16 + lr;
                int ob = rb * 64 + (((ks * 4 + g) ^ (rb & 7)) << 3);
                bf16x8 kbh = *(const bf16x8*)(sK + ob);
                bf16x8 kbl = *(const bf16x8*)(sKlo + ob);
                s[fj] = __builtin_amdgcn_mfma_f32_16x16x32_bf16(qah[ks], kbh, s[fj], 0, 0, 0);
                s[fj] = __builtin_amdgcn_mfma_f32_16x16x32_bf16(qah[ks], kbl, s[fj], 0, 0, 0);
                s[fj] = __builtin_amdgcn_mfma_f32_16x16x32_bf16(qal[ks], kbh, s[fj], 0, 0, 0);
            }
        }

        // ---- online softmax ----
        const bool domask = (k0 + 63) > wq0;
#pragma unroll
        for (int reg = 0; reg < 4; ++reg) {
            int qabs = wq0 + g * 4 + reg;
            float v4[4];
            float mloc = -INFINITY;
#pragma unroll
            for (int fj = 0; fj < 4; ++fj) {
                float sv = s[fj][reg] * 0.125f;
                if (domask && (k0 + fj * 16 + lr) > qabs) sv = -INFINITY;
                v4[fj] = sv;
                mloc = fmaxf(mloc, sv);
            }
            mloc = fmaxf(mloc, __shfl_xor(mloc, 1));
            mloc = fmaxf(mloc, __shfl_xor(mloc, 2));
            mloc = fmaxf(mloc, __shfl_xor(mloc, 4));
            mloc = fmaxf(mloc, __shfl_xor(mloc, 8));
            float mn = fmaxf(mrun[reg], mloc);
            float scx = __expf(mrun[reg] - mn);
            float rs = 0.f;
            float p[4];
#pragma unroll
            for (int fj = 0; fj < 4; ++fj) {
                p[fj] = __expf(v4[fj] - mn);
                rs += p[fj];
            }
            rs += __shfl_xor(rs, 1);
            rs += __shfl_xor(rs, 2);
            rs += __shfl_xor(rs, 4);
            rs += __shfl_xor(rs, 8);
            lrun[reg] = lrun[reg] * scx + rs;
            mrun[reg] = mn;
#pragma unroll
            for (int fd = 0; fd < 4; ++fd) o[fd][reg] *= scx;

            // write P (hi only; wave-private rows; swizzled)
            int prow = wid * 16 + g * 4 + reg;
#pragma unroll
            for (int fj = 0; fj < 4; ++fj) {
                int cc = fj * 16 + lr;
                int addr = prow * 64 + (((cc >> 3) ^ (prow & 7)) << 3) + (cc & 7);
                sP[addr] = f2bf(p[fj]);
            }
        }

        // ---- O += P V ----
        bf16x8 pa[2];
#pragma unroll
        for (int ks = 0; ks < 2; ++ks) {
            int rp = wid * 16 + lr;
            int off = rp * 64 + (((ks * 4 + g) ^ (rp & 7)) << 3);
            pa[ks] = *(const bf16x8*)(sP + off);
        }
#pragma unroll
        for (int fd = 0; fd < 4; ++fd)
#pragma unroll
            for (int ks = 0; ks < 2; ++ks) {
                int rv = fd * 16 + lr;
                int ob = rv * 64 + (((ks * 4 + g) ^ (rv & 7)) << 3);
                bf16x8 vb = *(const bf16x8*)(sV + ob);
                o[fd] = __builtin_amdgcn_mfma_f32_16x16x32_bf16(pa[ks], vb, o[fd], 0, 0, 0);
            }
    }

    // ---- epilogue: ctx split-bf16, [B, T, DM] ----
#pragma unroll
    for (int reg = 0; reg < 4; ++reg) {
        float inv = 1.f / lrun[reg];
        int t = q0 + wid * 16 + g * 4 + reg;
#pragma unroll
        for (int fd = 0; fd < 4; ++fd) {
            int d = fd * 16 + lr;
            float v = o[fd][reg] * inv;
            u16 hi = f2bf(v);
            u16 lo = f2bf(v - bf2f(hi));
            size_t oi = ((size_t)b * TB + t) * DM + h * HD + d;
            ctxh[oi] = hi;
            ctxl[oi] = lo;
        }
    }
}

// ---------------------------------------------------------------------------
extern "C" void kernel_launch(void* const* d_in, const int* in_sizes, int n_in,
                              void* d_out, int out_size, void* d_ws, size_t ws_size,
                              hipStream_t stream)
{
    const float* x  = (const float*)d_in[0];
    const float* Wq = (const float*)d_in[1];
    const float* Wk = (const float*)d_in[2];
    const float* Wv = (const float*)d_in[3];
    const float* Wo = (const float*)d_in[4];
    const float* bo = (const float*)d_in[5];
    float* out = (float*)d_out;

    u16* w = (u16*)d_ws;
    u16* xh   = w;                 // dead after qkv_gemm
    u16* xl   = w + SZE;
    u16* wt   = w + 2 * SZE;       // 8 WSZE == 1 SZE
    u16* qkvb = w + 3 * SZE;       // qh,ql,kh,kl,vth (5 SZE)
    u16* qh   = qkvb;
    u16* ql   = qkvb + SZE;
    u16* kh   = qkvb + 2 * SZE;
    u16* kl   = qkvb + 3 * SZE;
    u16* vth  = qkvb + 4 * SZE;
    u16* ctxh = xh;                // alias x-halves (dead by attn time)
    u16* ctxl = xl;

    convert_x<<<dim3(4096), 256, 0, stream>>>(x, xh, xl);
    convert_wt<<<dim3(16, 16, 4), 256, 0, stream>>>(Wq, Wk, Wv, Wo, wt);
    qkv_gemm<<<dim3(MROWS / 128, DM / 128, 3), 256, 0, stream>>>(xh, xl, wt, qkvb);
    attn_kernel<<<dim3(TB / QBLK, NH, NB), 512, 0, stream>>>(qh, ql, kh, kl, vth,
                                                             ctxh, ctxl);
    proj_gemm<<<dim3(MROWS / 128, DM / 128), 256, 0, stream>>>(
        ctxh, ctxl, wt + 3 * 2 * WSZE, wt + 3 * 2 * WSZE + WSZE, bo, out);
}

// Round 4
// 510.094 us; speedup vs baseline: 3.6237x; 1.0375x over previous
//
#include <hip/hip_runtime.h>
#include <math.h>

#define TB 2048
#define NB 4
#define NH 16
#define HD 64
#define DM 1024
#define MROWS (NB * TB) /* 8192 */
#define QBLK 128

typedef unsigned short u16;
typedef __attribute__((ext_vector_type(8))) _Float16 f16x8;
typedef __attribute__((ext_vector_type(8))) u16 u16x8;
typedef __attribute__((ext_vector_type(4))) u16 u16x4;
typedef __attribute__((ext_vector_type(4))) float f32x4;

#define SZE ((size_t)MROWS * DM) /* 8,388,608 elems */
#define WSZE ((size_t)DM * DM)   /* 1,048,576 elems */

// ---------------------------------------------------------------------------
__device__ __forceinline__ u16 f2h(float f) {
    _Float16 h = (_Float16)f; // v_cvt_f16_f32, RNE
    union { _Float16 h; u16 u; } c; c.h = h;
    return c.u;
}

__device__ __forceinline__ void gload16(const u16* g, u16* l) {
    __builtin_amdgcn_global_load_lds(
        (const __attribute__((address_space(1))) void*)g,
        (__attribute__((address_space(3))) void*)l, 16, 0, 0);
}

#define MFMA16(a, b, c) __builtin_amdgcn_mfma_f32_16x16x32_f16((a), (b), (c), 0, 0, 0)

// ---------------------------------------------------------------------------
// convert x -> fp16
// ---------------------------------------------------------------------------
__global__ __launch_bounds__(256) void convert_x(const float* __restrict__ x,
                                                 u16* __restrict__ xh)
{
    size_t i = ((size_t)blockIdx.x * 256 + threadIdx.x) * 8;
    float4 a = *(const float4*)(x + i);
    float4 b = *(const float4*)(x + i + 4);
    float v[8] = {a.x, a.y, a.z, a.w, b.x, b.y, b.z, b.w};
    u16x8 hi;
#pragma unroll
    for (int j = 0; j < 8; ++j) hi[j] = f2h(v[j]);
    *(u16x8*)(xh + i) = hi;
}

// ---------------------------------------------------------------------------
// convert + transpose weights: W[K][N] fp32 -> Wt [N][K] fp16
// ---------------------------------------------------------------------------
__global__ __launch_bounds__(256) void convert_wt(const float* __restrict__ Wq,
                                                  const float* __restrict__ Wk,
                                                  const float* __restrict__ Wv,
                                                  const float* __restrict__ Wo,
                                                  u16* __restrict__ wt)
{
    const int z = blockIdx.z;
    const float* W = (z == 0) ? Wq : (z == 1) ? Wk : (z == 2) ? Wv : Wo;
    u16* dh = wt + (size_t)z * WSZE;
    __shared__ float tile[64][65];
    const int tid = threadIdx.x;
    const int k0 = blockIdx.x * 64, n0 = blockIdx.y * 64;
#pragma unroll
    for (int i = 0; i < 4; ++i) {
        int c = i * 256 + tid, r = c >> 4, c4 = (c & 15) << 2;
        *(float4*)&tile[r][c4] = *(const float4*)&W[(size_t)(k0 + r) * DM + n0 + c4];
    }
    __syncthreads();
#pragma unroll
    for (int i = 0; i < 4; ++i) {
        int c = i * 256 + tid, n = c >> 4, k4 = (c & 15) << 2;
        u16x4 hi;
#pragma unroll
        for (int j = 0; j < 4; ++j) hi[j] = f2h(tile[k4 + j][n]);
        *(u16x4*)(dh + (size_t)(n0 + n) * DM + k0 + k4) = hi;
    }
}

// ---------------------------------------------------------------------------
// fp16 NT GEMM core (128x128 tile, BK=32, 4 waves 2x2)
// ---------------------------------------------------------------------------
__device__ __forceinline__ void gemm_nt_128(const u16* __restrict__ A,
                                            const u16* __restrict__ B,
                                            int bm, int bn, u16* lds,
                                            f32x4 acc[4][4])
{
    const int tid = threadIdx.x, lane = tid & 63;
    const int wid = tid >> 6, wm = wid >> 1, wn = wid & 1;
    const int lr = lane & 15, g = lane >> 4;
    u16* sA = lds;
    u16* sB = lds + 4096;

#pragma unroll
    for (int i = 0; i < 4; ++i)
#pragma unroll
        for (int j = 0; j < 4; ++j) acc[i][j] = (f32x4)0.f;

    for (int k0 = 0; k0 < DM; k0 += 32) {
        __syncthreads();
#pragma unroll
        for (int i = 0; i < 2; ++i) {
            int c = i * 256 + tid, r = c >> 2, db = c & 3;
            int src = db ^ ((r >> 1) & 3);
            size_t ga = (size_t)(bm + r) * DM + k0 + src * 8;
            size_t gb = (size_t)(bn + r) * DM + k0 + src * 8;
            gload16(A + ga, sA + c * 8);
            gload16(B + gb, sB + c * 8);
        }
        __syncthreads();

        f16x8 ah[4], bhv[4];
#pragma unroll
        for (int f = 0; f < 4; ++f) {
            int ra = wm * 64 + f * 16 + lr;
            int oa = ra * 32 + ((g ^ ((ra >> 1) & 3)) << 3);
            ah[f] = *(const f16x8*)(sA + oa);
            int rb = wn * 64 + f * 16 + lr;
            int ob = rb * 32 + ((g ^ ((rb >> 1) & 3)) << 3);
            bhv[f] = *(const f16x8*)(sB + ob);
        }
#pragma unroll
        for (int fi = 0; fi < 4; ++fi)
#pragma unroll
            for (int fj = 0; fj < 4; ++fj)
                acc[fi][fj] = MFMA16(ah[fi], bhv[fj], acc[fi][fj]);
    }
}

// QKV projections. z=0 -> Q [B,H,T,D]; z=1 -> K [B,H,T,D];
// z=2 -> V pre-transposed [B,H,D,T] (u16x4 packed stores). All fp16.
__global__ __launch_bounds__(256) void qkv_gemm(const u16* __restrict__ xh,
                                                const u16* __restrict__ wt,
                                                u16* __restrict__ qkvb)
{
    __shared__ u16 lds[8192];
    const int z = blockIdx.z;
    const u16* Bw = wt + (size_t)z * WSZE;
    const int bm = blockIdx.x * 128, bn = blockIdx.y * 128;

    f32x4 acc[4][4];
    gemm_nt_128(xh, Bw, bm, bn, lds, acc);

    const int lane = threadIdx.x & 63, wid = threadIdx.x >> 6;
    const int wm = wid >> 1, wn = wid & 1;
    const int lr = lane & 15, g = lane >> 4;

    if (z < 2) {
        u16* outh = qkvb + (size_t)z * SZE;
#pragma unroll
        for (int fi = 0; fi < 4; ++fi)
#pragma unroll
            for (int fj = 0; fj < 4; ++fj)
#pragma unroll
                for (int reg = 0; reg < 4; ++reg) {
                    int m = bm + wm * 64 + fi * 16 + g * 4 + reg;
                    int n = bn + wn * 64 + fj * 16 + lr;
                    int b = m >> 11, t = m & (TB - 1);
                    int h = n >> 6, d = n & 63;
                    size_t o = ((size_t)(b * NH + h) * TB + t) * HD + d;
                    outh[o] = f2h(acc[fi][fj][reg]);
                }
    } else {
        u16* vth = qkvb + (size_t)2 * SZE;
#pragma unroll
        for (int fi = 0; fi < 4; ++fi)
#pragma unroll
            for (int fj = 0; fj < 4; ++fj) {
                int n = bn + wn * 64 + fj * 16 + lr;
                int h = n >> 6, d = n & 63;
                int m0 = bm + wm * 64 + fi * 16 + g * 4;
                int b = m0 >> 11, t = m0 & (TB - 1);
                u16x4 v4;
#pragma unroll
                for (int reg = 0; reg < 4; ++reg) v4[reg] = f2h(acc[fi][fj][reg]);
                *(u16x4*)(vth + ((size_t)(b * NH + h) * HD + d) * TB + t) = v4;
            }
    }
}

// Output projection + bias -> fp32 out
__global__ __launch_bounds__(256) void proj_gemm(const u16* __restrict__ ch,
                                                 const u16* __restrict__ Bw,
                                                 const float* __restrict__ bo,
                                                 float* __restrict__ out)
{
    __shared__ u16 lds[8192];
    const int bm = blockIdx.x * 128, bn = blockIdx.y * 128;
    f32x4 acc[4][4];
    gemm_nt_128(ch, Bw, bm, bn, lds, acc);

    const int lane = threadIdx.x & 63, wid = threadIdx.x >> 6;
    const int wm = wid >> 1, wn = wid & 1;
    const int lr = lane & 15, g = lane >> 4;
#pragma unroll
    for (int fi = 0; fi < 4; ++fi)
#pragma unroll
        for (int fj = 0; fj < 4; ++fj) {
            int n = bn + wn * 64 + fj * 16 + lr;
            float bias = bo[n];
#pragma unroll
            for (int reg = 0; reg < 4; ++reg) {
                int m = bm + wm * 64 + fi * 16 + g * 4 + reg;
                out[(size_t)m * DM + n] = acc[fi][fj][reg] + bias;
            }
        }
}

// ---------------------------------------------------------------------------
// Flash attention, fp16 MFMA. QBLK=128, 8 waves; wave w owns q-rows w*16..+15.
// Q frags hoisted to registers. K/V double-buffered LDS, 1 barrier/tile.
// LDS = 2*16KB (K+V) + 16KB P = 48KB -> 3 blocks/CU.
// ---------------------------------------------------------------------------
__device__ __forceinline__ void stage_tile(const u16* __restrict__ Kh,
                                           const u16* __restrict__ Vth,
                                           size_t bh, int k0, u16* dst, int tid)
{
    int r = tid >> 3, sl = tid & 7;
    int src = sl ^ (r & 7);
    size_t gk = (bh * TB + k0 + r) * HD + src * 8;
    gload16(Kh + gk, dst + tid * 8);
    size_t gv = (bh * HD + r) * TB + k0 + src * 8;
    gload16(Vth + gv, dst + 4096 + tid * 8);
}

__global__ __launch_bounds__(512, 6) void attn_kernel(const u16* __restrict__ Qh,
                                                      const u16* __restrict__ Kh,
                                                      const u16* __restrict__ Vth,
                                                      u16* __restrict__ ctxh)
{
    __shared__ u16 lds[24576]; // buf0 @0 (K 4096 + V 4096), buf1 @8192, P @16384
    u16* sP = lds + 16384;     // [128][64]

    const int tid = threadIdx.x, lane = tid & 63, wid = tid >> 6;
    const int lr = lane & 15, g = lane >> 4;
    const int qi = (TB / QBLK - 1) - blockIdx.x; // heavy-first
    const int h = blockIdx.y, b = blockIdx.z;
    const int q0 = qi * QBLK;
    const size_t bh = (size_t)(b * NH + h);
    const int nt = 2 * qi + 2;
    const int wq0 = q0 + wid * 16;

    // hoisted Q fragments
    f16x8 qa[2];
    {
        size_t rowoff = (bh * TB + wq0 + lr) * HD;
#pragma unroll
        for (int ks = 0; ks < 2; ++ks)
            qa[ks] = *(const f16x8*)(Qh + rowoff + ks * 32 + g * 8);
    }

    f32x4 o[4];
    float mrun[4], lrun[4];
#pragma unroll
    for (int i = 0; i < 4; ++i) {
        o[i] = (f32x4)0.f;
        mrun[i] = -INFINITY;
        lrun[i] = 0.f;
    }

    stage_tile(Kh, Vth, bh, 0, lds, tid);

    for (int kt = 0; kt < nt; ++kt) {
        __syncthreads(); // drains vmcnt -> buf[kt&1] ready; prev readers done
        if (kt + 1 < nt)
            stage_tile(Kh, Vth, bh, (kt + 1) * 64, lds + ((kt + 1) & 1) * 8192, tid);

        const int k0 = kt * 64;
        if (k0 > wq0 + 15) continue; // wave fully masked

        u16* sK = lds + (kt & 1) * 8192;
        u16* sV = sK + 4096;

        // ---- S = Q K^T ----
        f32x4 s[4];
#pragma unroll
        for (int fj = 0; fj < 4; ++fj) {
            s[fj] = (f32x4)0.f;
#pragma unroll
            for (int ks = 0; ks < 2; ++ks) {
                int rb = fj * 16 + lr;
                int ob = rb * 64 + (((ks * 4 + g) ^ (rb & 7)) << 3);
                f16x8 kb = *(const f16x8*)(sK + ob);
                s[fj] = MFMA16(qa[ks], kb, s[fj]);
            }
        }

        // ---- online softmax ----
        const bool domask = (k0 + 63) > wq0;
#pragma unroll
        for (int reg = 0; reg < 4; ++reg) {
            int qabs = wq0 + g * 4 + reg;
            float v4[4];
            float mloc = -INFINITY;
#pragma unroll
            for (int fj = 0; fj < 4; ++fj) {
                float sv = s[fj][reg] * 0.125f;
                if (domask && (k0 + fj * 16 + lr) > qabs) sv = -INFINITY;
                v4[fj] = sv;
                mloc = fmaxf(mloc, sv);
            }
            mloc = fmaxf(mloc, __shfl_xor(mloc, 1));
            mloc = fmaxf(mloc, __shfl_xor(mloc, 2));
            mloc = fmaxf(mloc, __shfl_xor(mloc, 4));
            mloc = fmaxf(mloc, __shfl_xor(mloc, 8));
            float mn = fmaxf(mrun[reg], mloc);
            float scx = __expf(mrun[reg] - mn);
            float rs = 0.f;
            float p[4];
#pragma unroll
            for (int fj = 0; fj < 4; ++fj) {
                p[fj] = __expf(v4[fj] - mn);
                rs += p[fj];
            }
            rs += __shfl_xor(rs, 1);
            rs += __shfl_xor(rs, 2);
            rs += __shfl_xor(rs, 4);
            rs += __shfl_xor(rs, 8);
            lrun[reg] = lrun[reg] * scx + rs;
            mrun[reg] = mn;
#pragma unroll
            for (int fd = 0; fd < 4; ++fd) o[fd][reg] *= scx;

            int prow = wid * 16 + g * 4 + reg;
#pragma unroll
            for (int fj = 0; fj < 4; ++fj) {
                int cc = fj * 16 + lr;
                int addr = prow * 64 + (((cc >> 3) ^ (prow & 7)) << 3) + (cc & 7);
                sP[addr] = f2h(p[fj]);
            }
        }

        // ---- O += P V ----
        f16x8 pa[2];
#pragma unroll
        for (int ks = 0; ks < 2; ++ks) {
            int rp = wid * 16 + lr;
            int off = rp * 64 + (((ks * 4 + g) ^ (rp & 7)) << 3);
            pa[ks] = *(const f16x8*)(sP + off);
        }
#pragma unroll
        for (int fd = 0; fd < 4; ++fd)
#pragma unroll
            for (int ks = 0; ks < 2; ++ks) {
                int rv = fd * 16 + lr;
                int ob = rv * 64 + (((ks * 4 + g) ^ (rv & 7)) << 3);
                f16x8 vb = *(const f16x8*)(sV + ob);
                o[fd] = MFMA16(pa[ks], vb, o[fd]);
            }
    }

    // ---- epilogue: ctx fp16, [B, T, DM] ----
#pragma unroll
    for (int reg = 0; reg < 4; ++reg) {
        float inv = 1.f / lrun[reg];
        int t = q0 + wid * 16 + g * 4 + reg;
#pragma unroll
        for (int fd = 0; fd < 4; ++fd) {
            int d = fd * 16 + lr;
            size_t oi = ((size_t)b * TB + t) * DM + h * HD + d;
            ctxh[oi] = f2h(o[fd][reg] * inv);
        }
    }
}

// ---------------------------------------------------------------------------
extern "C" void kernel_launch(void* const* d_in, const int* in_sizes, int n_in,
                              void* d_out, int out_size, void* d_ws, size_t ws_size,
                              hipStream_t stream)
{
    const float* x  = (const float*)d_in[0];
    const float* Wq = (const float*)d_in[1];
    const float* Wk = (const float*)d_in[2];
    const float* Wv = (const float*)d_in[3];
    const float* Wo = (const float*)d_in[4];
    const float* bo = (const float*)d_in[5];
    float* out = (float*)d_out;

    u16* w = (u16*)d_ws;
    u16* xh   = w;                       // dead after qkv_gemm
    u16* wt   = w + SZE;                 // 4 * WSZE
    u16* qkvb = w + SZE + 4 * WSZE;      // q, k, vt (3 SZE)
    u16* qh   = qkvb;
    u16* kh   = qkvb + SZE;
    u16* vth  = qkvb + 2 * SZE;
    u16* ctxh = xh;                      // alias x (dead by attn time)

    convert_x<<<dim3(4096), 256, 0, stream>>>(x, xh);
    convert_wt<<<dim3(16, 16, 4), 256, 0, stream>>>(Wq, Wk, Wv, Wo, wt);
    qkv_gemm<<<dim3(MROWS / 128, DM / 128, 3), 256, 0, stream>>>(xh, wt, qkvb);
    attn_kernel<<<dim3(TB / QBLK, NH, NB), 512, 0, stream>>>(qh, kh, vth, ctxh);
    proj_gemm<<<dim3(MROWS / 128, DM / 128), 256, 0, stream>>>(
        ctxh, wt + 3 * WSZE, bo, out);
}

// Round 5
// 351.596 us; speedup vs baseline: 5.2572x; 1.4508x over previous
//
#include <hip/hip_runtime.h>
#include <math.h>

#define TB 2048
#define NB 4
#define NH 16
#define HD 64
#define DM 1024
#define MROWS (NB * TB) /* 8192 */
#define QBLK 128

typedef unsigned short u16;
typedef __attribute__((ext_vector_type(8))) _Float16 f16x8;
typedef __attribute__((ext_vector_type(8))) u16 u16x8;
typedef __attribute__((ext_vector_type(4))) u16 u16x4;
typedef __attribute__((ext_vector_type(4))) float f32x4;

#define SZE ((size_t)MROWS * DM) /* 8,388,608 elems */
#define WSZE ((size_t)DM * DM)   /* 1,048,576 elems */

// 1/sqrt(64) * log2(e): folded into Q so softmax uses exp2 directly
#define QSCALE 0.1803368801111204f
#define DEFER_THR 8.0f /* log2-units; P bounded by 2^8=256, fine in fp16 */

// ---------------------------------------------------------------------------
__device__ __forceinline__ u16 f2h(float f) {
    _Float16 h = (_Float16)f; // v_cvt_f16_f32, RNE
    union { _Float16 h; u16 u; } c; c.h = h;
    return c.u;
}

__device__ __forceinline__ void gload16(const u16* g, u16* l) {
    __builtin_amdgcn_global_load_lds(
        (const __attribute__((address_space(1))) void*)g,
        (__attribute__((address_space(3))) void*)l, 16, 0, 0);
}

#define MFMA16(a, b, c) __builtin_amdgcn_mfma_f32_16x16x32_f16((a), (b), (c), 0, 0, 0)

// ---------------------------------------------------------------------------
// convert x -> fp16
// ---------------------------------------------------------------------------
__global__ __launch_bounds__(256) void convert_x(const float* __restrict__ x,
                                                 u16* __restrict__ xh)
{
    size_t i = ((size_t)blockIdx.x * 256 + threadIdx.x) * 8;
    float4 a = *(const float4*)(x + i);
    float4 b = *(const float4*)(x + i + 4);
    float v[8] = {a.x, a.y, a.z, a.w, b.x, b.y, b.z, b.w};
    u16x8 hi;
#pragma unroll
    for (int j = 0; j < 8; ++j) hi[j] = f2h(v[j]);
    *(u16x8*)(xh + i) = hi;
}

// ---------------------------------------------------------------------------
// convert + transpose weights: W[K][N] fp32 -> Wt [N][K] fp16
// ---------------------------------------------------------------------------
__global__ __launch_bounds__(256) void convert_wt(const float* __restrict__ Wq,
                                                  const float* __restrict__ Wk,
                                                  const float* __restrict__ Wv,
                                                  const float* __restrict__ Wo,
                                                  u16* __restrict__ wt)
{
    const int z = blockIdx.z;
    const float* W = (z == 0) ? Wq : (z == 1) ? Wk : (z == 2) ? Wv : Wo;
    u16* dh = wt + (size_t)z * WSZE;
    __shared__ float tile[64][65];
    const int tid = threadIdx.x;
    const int k0 = blockIdx.x * 64, n0 = blockIdx.y * 64;
#pragma unroll
    for (int i = 0; i < 4; ++i) {
        int c = i * 256 + tid, r = c >> 4, c4 = (c & 15) << 2;
        *(float4*)&tile[r][c4] = *(const float4*)&W[(size_t)(k0 + r) * DM + n0 + c4];
    }
    __syncthreads();
#pragma unroll
    for (int i = 0; i < 4; ++i) {
        int c = i * 256 + tid, n = c >> 4, k4 = (c & 15) << 2;
        u16x4 hi;
#pragma unroll
        for (int j = 0; j < 4; ++j) hi[j] = f2h(tile[k4 + j][n]);
        *(u16x4*)(dh + (size_t)(n0 + n) * DM + k0 + k4) = hi;
    }
}

// ---------------------------------------------------------------------------
// fp16 NT GEMM core (128x128 tile, BK=32, 4 waves 2x2)
// ---------------------------------------------------------------------------
__device__ __forceinline__ void gemm_nt_128(const u16* __restrict__ A,
                                            const u16* __restrict__ B,
                                            int bm, int bn, u16* lds,
                                            f32x4 acc[4][4])
{
    const int tid = threadIdx.x, lane = tid & 63;
    const int wid = tid >> 6, wm = wid >> 1, wn = wid & 1;
    const int lr = lane & 15, g = lane >> 4;
    u16* sA = lds;
    u16* sB = lds + 4096;

#pragma unroll
    for (int i = 0; i < 4; ++i)
#pragma unroll
        for (int j = 0; j < 4; ++j) acc[i][j] = (f32x4)0.f;

    for (int k0 = 0; k0 < DM; k0 += 32) {
        __syncthreads();
#pragma unroll
        for (int i = 0; i < 2; ++i) {
            int c = i * 256 + tid, r = c >> 2, db = c & 3;
            int src = db ^ ((r >> 1) & 3);
            size_t ga = (size_t)(bm + r) * DM + k0 + src * 8;
            size_t gb = (size_t)(bn + r) * DM + k0 + src * 8;
            gload16(A + ga, sA + c * 8);
            gload16(B + gb, sB + c * 8);
        }
        __syncthreads();

        f16x8 ah[4], bhv[4];
#pragma unroll
        for (int f = 0; f < 4; ++f) {
            int ra = wm * 64 + f * 16 + lr;
            int oa = ra * 32 + ((g ^ ((ra >> 1) & 3)) << 3);
            ah[f] = *(const f16x8*)(sA + oa);
            int rb = wn * 64 + f * 16 + lr;
            int ob = rb * 32 + ((g ^ ((rb >> 1) & 3)) << 3);
            bhv[f] = *(const f16x8*)(sB + ob);
        }
#pragma unroll
        for (int fi = 0; fi < 4; ++fi)
#pragma unroll
            for (int fj = 0; fj < 4; ++fj)
                acc[fi][fj] = MFMA16(ah[fi], bhv[fj], acc[fi][fj]);
    }
}

// QKV projections. z=0 -> Q [B,H,T,D] (pre-scaled by QSCALE); z=1 -> K;
// z=2 -> V pre-transposed [B,H,D,T] (u16x4 packed stores). All fp16.
__global__ __launch_bounds__(256) void qkv_gemm(const u16* __restrict__ xh,
                                                const u16* __restrict__ wt,
                                                u16* __restrict__ qkvb)
{
    __shared__ u16 lds[8192];
    const int z = blockIdx.z;
    const u16* Bw = wt + (size_t)z * WSZE;
    const int bm = blockIdx.x * 128, bn = blockIdx.y * 128;

    f32x4 acc[4][4];
    gemm_nt_128(xh, Bw, bm, bn, lds, acc);

    const int lane = threadIdx.x & 63, wid = threadIdx.x >> 6;
    const int wm = wid >> 1, wn = wid & 1;
    const int lr = lane & 15, g = lane >> 4;

    if (z < 2) {
        const float scale = (z == 0) ? QSCALE : 1.0f;
        u16* outh = qkvb + (size_t)z * SZE;
#pragma unroll
        for (int fi = 0; fi < 4; ++fi)
#pragma unroll
            for (int fj = 0; fj < 4; ++fj)
#pragma unroll
                for (int reg = 0; reg < 4; ++reg) {
                    int m = bm + wm * 64 + fi * 16 + g * 4 + reg;
                    int n = bn + wn * 64 + fj * 16 + lr;
                    int b = m >> 11, t = m & (TB - 1);
                    int h = n >> 6, d = n & 63;
                    size_t o = ((size_t)(b * NH + h) * TB + t) * HD + d;
                    outh[o] = f2h(acc[fi][fj][reg] * scale);
                }
    } else {
        u16* vth = qkvb + (size_t)2 * SZE;
#pragma unroll
        for (int fi = 0; fi < 4; ++fi)
#pragma unroll
            for (int fj = 0; fj < 4; ++fj) {
                int n = bn + wn * 64 + fj * 16 + lr;
                int h = n >> 6, d = n & 63;
                int m0 = bm + wm * 64 + fi * 16 + g * 4;
                int b = m0 >> 11, t = m0 & (TB - 1);
                u16x4 v4;
#pragma unroll
                for (int reg = 0; reg < 4; ++reg) v4[reg] = f2h(acc[fi][fj][reg]);
                *(u16x4*)(vth + ((size_t)(b * NH + h) * HD + d) * TB + t) = v4;
            }
    }
}

// Output projection + bias -> fp32 out
__global__ __launch_bounds__(256) void proj_gemm(const u16* __restrict__ ch,
                                                 const u16* __restrict__ Bw,
                                                 const float* __restrict__ bo,
                                                 float* __restrict__ out)
{
    __shared__ u16 lds[8192];
    const int bm = blockIdx.x * 128, bn = blockIdx.y * 128;
    f32x4 acc[4][4];
    gemm_nt_128(ch, Bw, bm, bn, lds, acc);

    const int lane = threadIdx.x & 63, wid = threadIdx.x >> 6;
    const int wm = wid >> 1, wn = wid & 1;
    const int lr = lane & 15, g = lane >> 4;
#pragma unroll
    for (int fi = 0; fi < 4; ++fi)
#pragma unroll
        for (int fj = 0; fj < 4; ++fj) {
            int n = bn + wn * 64 + fj * 16 + lr;
            float bias = bo[n];
#pragma unroll
            for (int reg = 0; reg < 4; ++reg) {
                int m = bm + wm * 64 + fi * 16 + g * 4 + reg;
                out[(size_t)m * DM + n] = acc[fi][fj][reg] + bias;
            }
        }
}

// ---------------------------------------------------------------------------
// Flash attention, fp16 MFMA. QBLK=128, 8 waves; wave w owns q-rows w*16..+15.
// Q pre-scaled by 0.125*log2e -> exp2 softmax with defer-max (THR=8).
// XCD-aware 1-D grid: xcd = f&7 owns 8 (b,h) pairs (K/V stays in its L2).
// K/V double-buffered LDS, 1 barrier/tile. LDS 48KB -> 3 blocks/CU.
// ---------------------------------------------------------------------------
__device__ __forceinline__ void stage_tile(const u16* __restrict__ Kh,
                                           const u16* __restrict__ Vth,
                                           size_t bh, int k0, u16* dst, int tid)
{
    int r = tid >> 3, sl = tid & 7;
    int src = sl ^ (r & 7);
    size_t gk = (bh * TB + k0 + r) * HD + src * 8;
    gload16(Kh + gk, dst + tid * 8);
    size_t gv = (bh * HD + r) * TB + k0 + src * 8;
    gload16(Vth + gv, dst + 4096 + tid * 8);
}

__global__ __launch_bounds__(512, 4) void attn_kernel(const u16* __restrict__ Qh,
                                                      const u16* __restrict__ Kh,
                                                      const u16* __restrict__ Vth,
                                                      u16* __restrict__ ctxh)
{
    __shared__ u16 lds[24576]; // buf0 @0 (K 4096 + V 4096), buf1 @8192, P @16384
    u16* sP = lds + 16384;     // [128][64]

    const int tid = threadIdx.x, lane = tid & 63, wid = tid >> 6;
    const int lr = lane & 15, g = lane >> 4;

    // XCD-aware decode: f&7 = XCD (dispatch round-robins flat id across XCDs).
    // Each XCD owns 8 (b,h); within a (b,h), q-tiles run heavy-first.
    const int f = blockIdx.x;
    const int xcd = f & 7, slot = f >> 3;
    const int bh_idx = xcd * 8 + (slot >> 4);
    const int qi = 15 - (slot & 15);
    const int b = bh_idx >> 4, h = bh_idx & 15;

    const int q0 = qi * QBLK;
    const size_t bh = (size_t)(b * NH + h);
    const int nt = 2 * qi + 2;
    const int wq0 = q0 + wid * 16;

    // hoisted Q fragments (pre-scaled)
    f16x8 qa[2];
    {
        size_t rowoff = (bh * TB + wq0 + lr) * HD;
#pragma unroll
        for (int ks = 0; ks < 2; ++ks)
            qa[ks] = *(const f16x8*)(Qh + rowoff + ks * 32 + g * 8);
    }

    f32x4 o[4];
    float mrun[4], lrun[4];
#pragma unroll
    for (int i = 0; i < 4; ++i) {
        o[i] = (f32x4)0.f;
        mrun[i] = -INFINITY;
        lrun[i] = 0.f;
    }

    stage_tile(Kh, Vth, bh, 0, lds, tid);

    for (int kt = 0; kt < nt; ++kt) {
        __syncthreads(); // drains vmcnt -> buf[kt&1] ready; prev readers done
        if (kt + 1 < nt)
            stage_tile(Kh, Vth, bh, (kt + 1) * 64, lds + ((kt + 1) & 1) * 8192, tid);

        const int k0 = kt * 64;
        if (k0 > wq0 + 15) continue; // wave fully masked

        u16* sK = lds + (kt & 1) * 8192;
        u16* sV = sK + 4096;

        // ---- S = Q K^T (log2-scaled) ----
        f32x4 s[4];
#pragma unroll
        for (int fj = 0; fj < 4; ++fj) {
            s[fj] = (f32x4)0.f;
#pragma unroll
            for (int ks = 0; ks < 2; ++ks) {
                int rb = fj * 16 + lr;
                int ob = rb * 64 + (((ks * 4 + g) ^ (rb & 7)) << 3);
                f16x8 kb = *(const f16x8*)(sK + ob);
                s[fj] = MFMA16(qa[ks], kb, s[fj]);
            }
        }

        // ---- online softmax (exp2 domain, defer-max) ----
        const bool domask = (k0 + 63) > wq0;
#pragma unroll
        for (int reg = 0; reg < 4; ++reg) {
            int qabs = wq0 + g * 4 + reg;
            float v4[4];
            float mloc = -INFINITY;
#pragma unroll
            for (int fj = 0; fj < 4; ++fj) {
                float sv = s[fj][reg];
                if (domask && (k0 + fj * 16 + lr) > qabs) sv = -INFINITY;
                v4[fj] = sv;
                mloc = fmaxf(mloc, sv);
            }
            mloc = fmaxf(mloc, __shfl_xor(mloc, 1));
            mloc = fmaxf(mloc, __shfl_xor(mloc, 2));
            mloc = fmaxf(mloc, __shfl_xor(mloc, 4));
            mloc = fmaxf(mloc, __shfl_xor(mloc, 8));

            // defer-max: rescale only when max grew past THR (uniform per row)
            if (mloc > mrun[reg] + DEFER_THR) {
                float scx = exp2f(mrun[reg] - mloc);
                lrun[reg] *= scx;
#pragma unroll
                for (int fd = 0; fd < 4; ++fd) o[fd][reg] *= scx;
                mrun[reg] = mloc;
            }

            float rs = 0.f;
            float p[4];
#pragma unroll
            for (int fj = 0; fj < 4; ++fj) {
                p[fj] = exp2f(v4[fj] - mrun[reg]);
                rs += p[fj];
            }
            rs += __shfl_xor(rs, 1);
            rs += __shfl_xor(rs, 2);
            rs += __shfl_xor(rs, 4);
            rs += __shfl_xor(rs, 8);
            lrun[reg] += rs;

            int prow = wid * 16 + g * 4 + reg;
#pragma unroll
            for (int fj = 0; fj < 4; ++fj) {
                int cc = fj * 16 + lr;
                int addr = prow * 64 + (((cc >> 3) ^ (prow & 7)) << 3) + (cc & 7);
                sP[addr] = f2h(p[fj]);
            }
        }

        // ---- O += P V ----
        f16x8 pa[2];
#pragma unroll
        for (int ks = 0; ks < 2; ++ks) {
            int rp = wid * 16 + lr;
            int off = rp * 64 + (((ks * 4 + g) ^ (rp & 7)) << 3);
            pa[ks] = *(const f16x8*)(sP + off);
        }
#pragma unroll
        for (int fd = 0; fd < 4; ++fd)
#pragma unroll
            for (int ks = 0; ks < 2; ++ks) {
                int rv = fd * 16 + lr;
                int ob = rv * 64 + (((ks * 4 + g) ^ (rv & 7)) << 3);
                f16x8 vb = *(const f16x8*)(sV + ob);
                o[fd] = MFMA16(pa[ks], vb, o[fd]);
            }
    }

    // ---- epilogue: ctx fp16, [B, T, DM] ----
#pragma unroll
    for (int reg = 0; reg < 4; ++reg) {
        float inv = 1.f / lrun[reg];
        int t = q0 + wid * 16 + g * 4 + reg;
#pragma unroll
        for (int fd = 0; fd < 4; ++fd) {
            int d = fd * 16 + lr;
            size_t oi = ((size_t)b * TB + t) * DM + h * HD + d;
            ctxh[oi] = f2h(o[fd][reg] * inv);
        }
    }
}

// ---------------------------------------------------------------------------
extern "C" void kernel_launch(void* const* d_in, const int* in_sizes, int n_in,
                              void* d_out, int out_size, void* d_ws, size_t ws_size,
                              hipStream_t stream)
{
    const float* x  = (const float*)d_in[0];
    const float* Wq = (const float*)d_in[1];
    const float* Wk = (const float*)d_in[2];
    const float* Wv = (const float*)d_in[3];
    const float* Wo = (const float*)d_in[4];
    const float* bo = (const float*)d_in[5];
    float* out = (float*)d_out;

    u16* w = (u16*)d_ws;
    u16* xh   = w;                       // dead after qkv_gemm
    u16* wt   = w + SZE;                 // 4 * WSZE
    u16* qkvb = w + SZE + 4 * WSZE;      // q, k, vt (3 SZE)
    u16* qh   = qkvb;
    u16* kh   = qkvb + SZE;
    u16* vth  = qkvb + 2 * SZE;
    u16* ctxh = xh;                      // alias x (dead by attn time)

    convert_x<<<dim3(4096), 256, 0, stream>>>(x, xh);
    convert_wt<<<dim3(16, 16, 4), 256, 0, stream>>>(Wq, Wk, Wv, Wo, wt);
    qkv_gemm<<<dim3(MROWS / 128, DM / 128, 3), 256, 0, stream>>>(xh, wt, qkvb);
    attn_kernel<<<dim3(TB / QBLK * NH * NB), 512, 0, stream>>>(qh, kh, vth, ctxh);
    proj_gemm<<<dim3(MROWS / 128, DM / 128), 256, 0, stream>>>(
        ctxh, wt + 3 * WSZE, bo, out);
}

// Round 7
// 284.811 us; speedup vs baseline: 6.4899x; 1.2345x over previous
//
#include <hip/hip_runtime.h>
#include <math.h>

#define TB 2048
#define NB 4
#define NH 16
#define HD 64
#define DM 1024
#define MROWS (NB * TB) /* 8192 */
#define QBLK 128

typedef unsigned short u16;
typedef __attribute__((ext_vector_type(8))) _Float16 f16x8;
typedef __attribute__((ext_vector_type(2))) __fp16 fp16x2; // cvt_pkrtz return type
typedef __attribute__((ext_vector_type(8))) u16 u16x8;
typedef __attribute__((ext_vector_type(4))) u16 u16x4;
typedef __attribute__((ext_vector_type(4))) float f32x4;

#define SZE ((size_t)MROWS * DM) /* 8,388,608 elems */
#define WSZE ((size_t)DM * DM)   /* 1,048,576 elems */

// 1/sqrt(64) * log2(e): folded into Q so softmax uses exp2 directly
#define QSCALE 0.1803368801111204f
#define DEFER_THR 8.0f /* log2-units; P bounded by 2^8=256, fine in fp16 */

// LDS column swizzle: uniform 8-slot spread for both sigma-permuted K reads
// (row bits: rem in b0-1, group in b3) and V reads (lr in b0-3).
#define PHI(r) ((((r) & 3) << 1) | (((r) >> 3) & 1))

// ---------------------------------------------------------------------------
__device__ __forceinline__ u16 f2h(float f) {
    _Float16 h = (_Float16)f; // v_cvt_f16_f32, RNE
    union { _Float16 h; u16 u; } c; c.h = h;
    return c.u;
}

__device__ __forceinline__ void gload16(const u16* g, u16* l) {
    __builtin_amdgcn_global_load_lds(
        (const __attribute__((address_space(1))) void*)g,
        (__attribute__((address_space(3))) void*)l, 16, 0, 0);
}

#define MFMA16(a, b, c) __builtin_amdgcn_mfma_f32_16x16x32_f16((a), (b), (c), 0, 0, 0)

// ---------------------------------------------------------------------------
// convert x -> fp16
// ---------------------------------------------------------------------------
__global__ __launch_bounds__(256) void convert_x(const float* __restrict__ x,
                                                 u16* __restrict__ xh)
{
    size_t i = ((size_t)blockIdx.x * 256 + threadIdx.x) * 8;
    float4 a = *(const float4*)(x + i);
    float4 b = *(const float4*)(x + i + 4);
    float v[8] = {a.x, a.y, a.z, a.w, b.x, b.y, b.z, b.w};
    u16x8 hi;
#pragma unroll
    for (int j = 0; j < 8; ++j) hi[j] = f2h(v[j]);
    *(u16x8*)(xh + i) = hi;
}

// ---------------------------------------------------------------------------
// convert + transpose weights: W[K][N] fp32 -> Wt [N][K] fp16
// ---------------------------------------------------------------------------
__global__ __launch_bounds__(256) void convert_wt(const float* __restrict__ Wq,
                                                  const float* __restrict__ Wk,
                                                  const float* __restrict__ Wv,
                                                  const float* __restrict__ Wo,
                                                  u16* __restrict__ wt)
{
    const int z = blockIdx.z;
    const float* W = (z == 0) ? Wq : (z == 1) ? Wk : (z == 2) ? Wv : Wo;
    u16* dh = wt + (size_t)z * WSZE;
    __shared__ float tile[64][65];
    const int tid = threadIdx.x;
    const int k0 = blockIdx.x * 64, n0 = blockIdx.y * 64;
#pragma unroll
    for (int i = 0; i < 4; ++i) {
        int c = i * 256 + tid, r = c >> 4, c4 = (c & 15) << 2;
        *(float4*)&tile[r][c4] = *(const float4*)&W[(size_t)(k0 + r) * DM + n0 + c4];
    }
    __syncthreads();
#pragma unroll
    for (int i = 0; i < 4; ++i) {
        int c = i * 256 + tid, n = c >> 4, k4 = (c & 15) << 2;
        u16x4 hi;
#pragma unroll
        for (int j = 0; j < 4; ++j) hi[j] = f2h(tile[k4 + j][n]);
        *(u16x4*)(dh + (size_t)(n0 + n) * DM + k0 + k4) = hi;
    }
}

// ---------------------------------------------------------------------------
// fp16 NT GEMM core (128x128 tile, BK=32, 4 waves 2x2)
// ---------------------------------------------------------------------------
__device__ __forceinline__ void gemm_nt_128(const u16* __restrict__ A,
                                            const u16* __restrict__ B,
                                            int bm, int bn, u16* lds,
                                            f32x4 acc[4][4])
{
    const int tid = threadIdx.x, lane = tid & 63;
    const int wid = tid >> 6, wm = wid >> 1, wn = wid & 1;
    const int lr = lane & 15, g = lane >> 4;
    u16* sA = lds;
    u16* sB = lds + 4096;

#pragma unroll
    for (int i = 0; i < 4; ++i)
#pragma unroll
        for (int j = 0; j < 4; ++j) acc[i][j] = (f32x4)0.f;

    for (int k0 = 0; k0 < DM; k0 += 32) {
        __syncthreads();
#pragma unroll
        for (int i = 0; i < 2; ++i) {
            int c = i * 256 + tid, r = c >> 2, db = c & 3;
            int src = db ^ ((r >> 1) & 3);
            size_t ga = (size_t)(bm + r) * DM + k0 + src * 8;
            size_t gb = (size_t)(bn + r) * DM + k0 + src * 8;
            gload16(A + ga, sA + c * 8);
            gload16(B + gb, sB + c * 8);
        }
        __syncthreads();

        f16x8 ah[4], bhv[4];
#pragma unroll
        for (int f = 0; f < 4; ++f) {
            int ra = wm * 64 + f * 16 + lr;
            int oa = ra * 32 + ((g ^ ((ra >> 1) & 3)) << 3);
            ah[f] = *(const f16x8*)(sA + oa);
            int rb = wn * 64 + f * 16 + lr;
            int ob = rb * 32 + ((g ^ ((rb >> 1) & 3)) << 3);
            bhv[f] = *(const f16x8*)(sB + ob);
        }
#pragma unroll
        for (int fi = 0; fi < 4; ++fi)
#pragma unroll
            for (int fj = 0; fj < 4; ++fj)
                acc[fi][fj] = MFMA16(ah[fi], bhv[fj], acc[fi][fj]);
    }
}

// QKV projections. z=0 -> Q [B,H,T,D] (pre-scaled by QSCALE); z=1 -> K;
// z=2 -> V pre-transposed [B,H,D,T] (u16x4 packed stores). All fp16.
__global__ __launch_bounds__(256) void qkv_gemm(const u16* __restrict__ xh,
                                                const u16* __restrict__ wt,
                                                u16* __restrict__ qkvb)
{
    __shared__ u16 lds[8192];
    const int z = blockIdx.z;
    const u16* Bw = wt + (size_t)z * WSZE;
    const int bm = blockIdx.x * 128, bn = blockIdx.y * 128;

    f32x4 acc[4][4];
    gemm_nt_128(xh, Bw, bm, bn, lds, acc);

    const int lane = threadIdx.x & 63, wid = threadIdx.x >> 6;
    const int wm = wid >> 1, wn = wid & 1;
    const int lr = lane & 15, g = lane >> 4;

    if (z < 2) {
        const float scale = (z == 0) ? QSCALE : 1.0f;
        u16* outh = qkvb + (size_t)z * SZE;
#pragma unroll
        for (int fi = 0; fi < 4; ++fi)
#pragma unroll
            for (int fj = 0; fj < 4; ++fj)
#pragma unroll
                for (int reg = 0; reg < 4; ++reg) {
                    int m = bm + wm * 64 + fi * 16 + g * 4 + reg;
                    int n = bn + wn * 64 + fj * 16 + lr;
                    int b = m >> 11, t = m & (TB - 1);
                    int h = n >> 6, d = n & 63;
                    size_t o = ((size_t)(b * NH + h) * TB + t) * HD + d;
                    outh[o] = f2h(acc[fi][fj][reg] * scale);
                }
    } else {
        u16* vth = qkvb + (size_t)2 * SZE;
#pragma unroll
        for (int fi = 0; fi < 4; ++fi)
#pragma unroll
            for (int fj = 0; fj < 4; ++fj) {
                int n = bn + wn * 64 + fj * 16 + lr;
                int h = n >> 6, d = n & 63;
                int m0 = bm + wm * 64 + fi * 16 + g * 4;
                int b = m0 >> 11, t = m0 & (TB - 1);
                u16x4 v4;
#pragma unroll
                for (int reg = 0; reg < 4; ++reg) v4[reg] = f2h(acc[fi][fj][reg]);
                *(u16x4*)(vth + ((size_t)(b * NH + h) * HD + d) * TB + t) = v4;
            }
    }
}

// Output projection + bias -> fp32 out
__global__ __launch_bounds__(256) void proj_gemm(const u16* __restrict__ ch,
                                                 const u16* __restrict__ Bw,
                                                 const float* __restrict__ bo,
                                                 float* __restrict__ out)
{
    __shared__ u16 lds[8192];
    const int bm = blockIdx.x * 128, bn = blockIdx.y * 128;
    f32x4 acc[4][4];
    gemm_nt_128(ch, Bw, bm, bn, lds, acc);

    const int lane = threadIdx.x & 63, wid = threadIdx.x >> 6;
    const int wm = wid >> 1, wn = wid & 1;
    const int lr = lane & 15, g = lane >> 4;
#pragma unroll
    for (int fi = 0; fi < 4; ++fi)
#pragma unroll
        for (int fj = 0; fj < 4; ++fj) {
            int n = bn + wn * 64 + fj * 16 + lr;
            float bias = bo[n];
#pragma unroll
            for (int reg = 0; reg < 4; ++reg) {
                int m = bm + wm * 64 + fi * 16 + g * 4 + reg;
                out[(size_t)m * DM + n] = acc[fi][fj][reg] + bias;
            }
        }
}

// ---------------------------------------------------------------------------
// Flash attention, swapped-operand fp16 MFMA.
//   S^T = mfma(K, Q): lane (g,lr) owns q-row (wq0+lr), keys
//     key(fj,reg) = 32*(fj>>1) + 8*g + 4*(fj&1) + reg   (sigma-permuted K rows)
//   -> softmax lane-local (16 vals) + 2 shfl_xor; P stays in registers and IS
//      the PV B-fragment (k-slot g*8+j == key 32ks+8g+j).
//   O^T = mfma(Vt, P^T): same Vt LDS reads as before; no P LDS buffer at all.
// K/V double-buffered LDS (32KB), 1 barrier/tile, XCD-aware 1-D grid.
// ---------------------------------------------------------------------------
__device__ __forceinline__ void stage_tile(const u16* __restrict__ Kh,
                                           const u16* __restrict__ Vth,
                                           size_t bh, int k0, u16* dst, int tid)
{
    int r = tid >> 3, sl = tid & 7;
    int src = sl ^ PHI(r);
    size_t gk = (bh * TB + k0 + r) * HD + src * 8;
    gload16(Kh + gk, dst + tid * 8);
    size_t gv = (bh * HD + r) * TB + k0 + src * 8;
    gload16(Vth + gv, dst + 4096 + tid * 8);
}

__global__ __launch_bounds__(512, 4) void attn_kernel(const u16* __restrict__ Qh,
                                                      const u16* __restrict__ Kh,
                                                      const u16* __restrict__ Vth,
                                                      u16* __restrict__ ctxh)
{
    __shared__ u16 lds[16384]; // buf0: K@0 V@4096; buf1: K@8192 V@12288

    const int tid = threadIdx.x, lane = tid & 63, wid = tid >> 6;
    const int lr = lane & 15, g = lane >> 4;

    // XCD-aware decode: f&7 = XCD; each XCD owns 8 (b,h) with all q-tiles.
    const int f = blockIdx.x;
    const int xcd = f & 7, slot = f >> 3;
    const int bh_idx = xcd * 8 + (slot >> 4);
    const int qi = 15 - (slot & 15); // heavy-first
    const int b = bh_idx >> 4, h = bh_idx & 15;

    const int q0 = qi * QBLK;
    const size_t bh = (size_t)(b * NH + h);
    const int nt = 2 * qi + 2;
    const int wq0 = q0 + wid * 16;
    const int qrow = wq0 + lr; // this lane's q-row

    // hoisted Q fragments (pre-scaled by QSCALE*log2e)
    f16x8 qa[2];
    {
        size_t rowoff = (bh * TB + qrow) * HD;
#pragma unroll
        for (int ks = 0; ks < 2; ++ks)
            qa[ks] = *(const f16x8*)(Qh + rowoff + ks * 32 + g * 8);
    }

    f32x4 o[4];
#pragma unroll
    for (int i = 0; i < 4; ++i) o[i] = (f32x4)0.f;
    float mrun = -INFINITY, lrun = 0.f;

    stage_tile(Kh, Vth, bh, 0, lds, tid);

    for (int kt = 0; kt < nt; ++kt) {
        __syncthreads(); // drains vmcnt -> buf[kt&1] ready; prev readers done
        if (kt + 1 < nt)
            stage_tile(Kh, Vth, bh, (kt + 1) * 64, lds + ((kt + 1) & 1) * 8192, tid);

        const int k0 = kt * 64;
        if (k0 > wq0 + 15) continue; // wave fully masked (last tile, low waves)

        u16* sK = lds + (kt & 1) * 8192;
        u16* sV = sK + 4096;

        // ---- S^T = K Q (sigma-permuted A rows) ----
        f32x4 s[4];
#pragma unroll
        for (int fj = 0; fj < 4; ++fj) {
            s[fj] = (f32x4)0.f;
            int R = 32 * (fj >> 1) + 8 * (lr >> 2) + 4 * (fj & 1) + (lr & 3);
#pragma unroll
            for (int ks = 0; ks < 2; ++ks) {
                int sl = (ks * 4 + g) ^ PHI(R);
                f16x8 kb = *(const f16x8*)(sK + R * 64 + sl * 8);
                s[fj] = MFMA16(kb, qa[ks], s[fj]);
            }
        }

        // ---- causal mask (key index is static per lane) ----
        if ((k0 + 63) > wq0) {
#pragma unroll
            for (int fj = 0; fj < 4; ++fj)
#pragma unroll
                for (int reg = 0; reg < 4; ++reg) {
                    int key = k0 + 32 * (fj >> 1) + 8 * g + 4 * (fj & 1) + reg;
                    if (key > qrow) s[fj][reg] = -INFINITY;
                }
        }

        // ---- online softmax: lane-local 16 + 2 shfl; defer-max ----
        float mloc = -INFINITY;
#pragma unroll
        for (int fj = 0; fj < 4; ++fj)
#pragma unroll
            for (int reg = 0; reg < 4; ++reg) mloc = fmaxf(mloc, s[fj][reg]);
        mloc = fmaxf(mloc, __shfl_xor(mloc, 16));
        mloc = fmaxf(mloc, __shfl_xor(mloc, 32));

        if (mloc > mrun + DEFER_THR) {
            float scx = exp2f(mrun - mloc);
            lrun *= scx;
#pragma unroll
            for (int fd = 0; fd < 4; ++fd) o[fd] *= scx;
            mrun = mloc;
        }

        float p[4][4];
        float rs = 0.f;
#pragma unroll
        for (int fj = 0; fj < 4; ++fj)
#pragma unroll
            for (int reg = 0; reg < 4; ++reg) {
                p[fj][reg] = exp2f(s[fj][reg] - mrun);
                rs += p[fj][reg];
            }
        rs += __shfl_xor(rs, 16);
        rs += __shfl_xor(rs, 32);
        lrun += rs;

        // ---- pack P -> PV B-fragments (lane-local, no LDS) ----
        union { f16x8 v8; fp16x2 v2[4]; } pb0, pb1;
        pb0.v2[0] = __builtin_amdgcn_cvt_pkrtz(p[0][0], p[0][1]);
        pb0.v2[1] = __builtin_amdgcn_cvt_pkrtz(p[0][2], p[0][3]);
        pb0.v2[2] = __builtin_amdgcn_cvt_pkrtz(p[1][0], p[1][1]);
        pb0.v2[3] = __builtin_amdgcn_cvt_pkrtz(p[1][2], p[1][3]);
        pb1.v2[0] = __builtin_amdgcn_cvt_pkrtz(p[2][0], p[2][1]);
        pb1.v2[1] = __builtin_amdgcn_cvt_pkrtz(p[2][2], p[2][3]);
        pb1.v2[2] = __builtin_amdgcn_cvt_pkrtz(p[3][0], p[3][1]);
        pb1.v2[3] = __builtin_amdgcn_cvt_pkrtz(p[3][2], p[3][3]);

        // ---- O^T += Vt P^T ----
#pragma unroll
        for (int fd = 0; fd < 4; ++fd) {
            int Rv = fd * 16 + lr;
#pragma unroll
            for (int ks = 0; ks < 2; ++ks) {
                int sl = (ks * 4 + g) ^ PHI(Rv);
                f16x8 vb = *(const f16x8*)(sV + Rv * 64 + sl * 8);
                o[fd] = MFMA16(vb, ks ? pb1.v8 : pb0.v8, o[fd]);
            }
        }
    }

    // ---- epilogue: lane (g,lr) holds O[qrow][d = fd*16+4g+reg] ----
    float inv = 1.f / lrun;
#pragma unroll
    for (int fd = 0; fd < 4; ++fd) {
        u16x4 st;
#pragma unroll
        for (int reg = 0; reg < 4; ++reg) st[reg] = f2h(o[fd][reg] * inv);
        int d = fd * 16 + 4 * g;
        *(u16x4*)(ctxh + ((size_t)b * TB + qrow) * DM + h * HD + d) = st;
    }
}

// ---------------------------------------------------------------------------
extern "C" void kernel_launch(void* const* d_in, const int* in_sizes, int n_in,
                              void* d_out, int out_size, void* d_ws, size_t ws_size,
                              hipStream_t stream)
{
    const float* x  = (const float*)d_in[0];
    const float* Wq = (const float*)d_in[1];
    const float* Wk = (const float*)d_in[2];
    const float* Wv = (const float*)d_in[3];
    const float* Wo = (const float*)d_in[4];
    const float* bo = (const float*)d_in[5];
    float* out = (float*)d_out;

    u16* w = (u16*)d_ws;
    u16* xh   = w;                       // dead after qkv_gemm
    u16* wt   = w + SZE;                 // 4 * WSZE
    u16* qkvb = w + SZE + 4 * WSZE;      // q, k, vt (3 SZE)
    u16* qh   = qkvb;
    u16* kh   = qkvb + SZE;
    u16* vth  = qkvb + 2 * SZE;
    u16* ctxh = xh;                      // alias x (dead by attn time)

    convert_x<<<dim3(4096), 256, 0, stream>>>(x, xh);
    convert_wt<<<dim3(16, 16, 4), 256, 0, stream>>>(Wq, Wk, Wv, Wo, wt);
    qkv_gemm<<<dim3(MROWS / 128, DM / 128, 3), 256, 0, stream>>>(xh, wt, qkvb);
    attn_kernel<<<dim3(TB / QBLK * NH * NB), 512, 0, stream>>>(qh, kh, vth, ctxh);
    proj_gemm<<<dim3(MROWS / 128, DM / 128), 256, 0, stream>>>(
        ctxh, wt + 3 * WSZE, bo, out);
}

// Round 8
// 264.830 us; speedup vs baseline: 6.9796x; 1.0754x over previous
//
#include <hip/hip_runtime.h>
#include <math.h>

#define TB 2048
#define NB 4
#define NH 16
#define HD 64
#define DM 1024
#define MROWS (NB * TB) /* 8192 */
#define QBLK 128

typedef unsigned short u16;
typedef __attribute__((ext_vector_type(8))) _Float16 f16x8;
typedef __attribute__((ext_vector_type(2))) __fp16 fp16x2; // cvt_pkrtz return type
typedef __attribute__((ext_vector_type(8))) u16 u16x8;
typedef __attribute__((ext_vector_type(4))) u16 u16x4;
typedef __attribute__((ext_vector_type(4))) float f32x4;

#define SZE ((size_t)MROWS * DM) /* 8,388,608 elems */
#define WSZE ((size_t)DM * DM)   /* 1,048,576 elems */

// 1/sqrt(64) * log2(e): folded into Q so softmax uses exp2 directly
#define QSCALE 0.1803368801111204f
#define DEFER_THR 8.0f /* log2-units; P bounded by 2^8=256, fine in fp16 */

// LDS column swizzle: uniform 8-slot spread for both sigma-permuted K reads
// (row bits: rem in b0-1, group in b3) and V reads (lr in b0-3).
#define PHI(r) ((((r) & 3) << 1) | (((r) >> 3) & 1))

// ---------------------------------------------------------------------------
__device__ __forceinline__ u16 f2h(float f) {
    _Float16 h = (_Float16)f; // v_cvt_f16_f32, RNE
    union { _Float16 h; u16 u; } c; c.h = h;
    return c.u;
}

__device__ __forceinline__ void gload16(const u16* g, u16* l) {
    __builtin_amdgcn_global_load_lds(
        (const __attribute__((address_space(1))) void*)g,
        (__attribute__((address_space(3))) void*)l, 16, 0, 0);
}

#define MFMA16(a, b, c) __builtin_amdgcn_mfma_f32_16x16x32_f16((a), (b), (c), 0, 0, 0)

// ---------------------------------------------------------------------------
// convert x -> fp16
// ---------------------------------------------------------------------------
__global__ __launch_bounds__(256) void convert_x(const float* __restrict__ x,
                                                 u16* __restrict__ xh)
{
    size_t i = ((size_t)blockIdx.x * 256 + threadIdx.x) * 8;
    float4 a = *(const float4*)(x + i);
    float4 b = *(const float4*)(x + i + 4);
    float v[8] = {a.x, a.y, a.z, a.w, b.x, b.y, b.z, b.w};
    u16x8 hi;
#pragma unroll
    for (int j = 0; j < 8; ++j) hi[j] = f2h(v[j]);
    *(u16x8*)(xh + i) = hi;
}

// ---------------------------------------------------------------------------
// convert + transpose weights: W[K][N] fp32 -> Wt [N][K] fp16
// ---------------------------------------------------------------------------
__global__ __launch_bounds__(256) void convert_wt(const float* __restrict__ Wq,
                                                  const float* __restrict__ Wk,
                                                  const float* __restrict__ Wv,
                                                  const float* __restrict__ Wo,
                                                  u16* __restrict__ wt)
{
    const int z = blockIdx.z;
    const float* W = (z == 0) ? Wq : (z == 1) ? Wk : (z == 2) ? Wv : Wo;
    u16* dh = wt + (size_t)z * WSZE;
    __shared__ float tile[64][65];
    const int tid = threadIdx.x;
    const int k0 = blockIdx.x * 64, n0 = blockIdx.y * 64;
#pragma unroll
    for (int i = 0; i < 4; ++i) {
        int c = i * 256 + tid, r = c >> 4, c4 = (c & 15) << 2;
        *(float4*)&tile[r][c4] = *(const float4*)&W[(size_t)(k0 + r) * DM + n0 + c4];
    }
    __syncthreads();
#pragma unroll
    for (int i = 0; i < 4; ++i) {
        int c = i * 256 + tid, n = c >> 4, k4 = (c & 15) << 2;
        u16x4 hi;
#pragma unroll
        for (int j = 0; j < 4; ++j) hi[j] = f2h(tile[k4 + j][n]);
        *(u16x4*)(dh + (size_t)(n0 + n) * DM + k0 + k4) = hi;
    }
}

// ---------------------------------------------------------------------------
// fp16 NT GEMM core (128x128 tile, BK=32, 4 waves 2x2)
// ---------------------------------------------------------------------------
__device__ __forceinline__ void gemm_nt_128(const u16* __restrict__ A,
                                            const u16* __restrict__ B,
                                            int bm, int bn, u16* lds,
                                            f32x4 acc[4][4])
{
    const int tid = threadIdx.x, lane = tid & 63;
    const int wid = tid >> 6, wm = wid >> 1, wn = wid & 1;
    const int lr = lane & 15, g = lane >> 4;
    u16* sA = lds;
    u16* sB = lds + 4096;

#pragma unroll
    for (int i = 0; i < 4; ++i)
#pragma unroll
        for (int j = 0; j < 4; ++j) acc[i][j] = (f32x4)0.f;

    for (int k0 = 0; k0 < DM; k0 += 32) {
        __syncthreads();
#pragma unroll
        for (int i = 0; i < 2; ++i) {
            int c = i * 256 + tid, r = c >> 2, db = c & 3;
            int src = db ^ ((r >> 1) & 3);
            size_t ga = (size_t)(bm + r) * DM + k0 + src * 8;
            size_t gb = (size_t)(bn + r) * DM + k0 + src * 8;
            gload16(A + ga, sA + c * 8);
            gload16(B + gb, sB + c * 8);
        }
        __syncthreads();

        f16x8 ah[4], bhv[4];
#pragma unroll
        for (int f = 0; f < 4; ++f) {
            int ra = wm * 64 + f * 16 + lr;
            int oa = ra * 32 + ((g ^ ((ra >> 1) & 3)) << 3);
            ah[f] = *(const f16x8*)(sA + oa);
            int rb = wn * 64 + f * 16 + lr;
            int ob = rb * 32 + ((g ^ ((rb >> 1) & 3)) << 3);
            bhv[f] = *(const f16x8*)(sB + ob);
        }
        __builtin_amdgcn_s_setprio(1);
#pragma unroll
        for (int fi = 0; fi < 4; ++fi)
#pragma unroll
            for (int fj = 0; fj < 4; ++fj)
                acc[fi][fj] = MFMA16(ah[fi], bhv[fj], acc[fi][fj]);
        __builtin_amdgcn_s_setprio(0);
    }
}

// QKV projections, XCD-aware 1-D grid (1536 blocks):
//   xcd = f&7 owns M-strip rows xcd*1024..+1023 (A-strip 2MB stays in its L2);
//   within XCD: (z,nt) outer, mt inner -> each B-panel fetched once.
// z=0 -> Q [B,H,T,D] (pre-scaled by QSCALE); z=1 -> K; z=2 -> V transposed.
__global__ __launch_bounds__(256) void qkv_gemm(const u16* __restrict__ xh,
                                                const u16* __restrict__ wt,
                                                u16* __restrict__ qkvb)
{
    __shared__ u16 lds[8192];
    const int f = blockIdx.x;
    const int xcd = f & 7, s = f >> 3;   // s: 0..191
    const int ntz = s >> 3;              // 0..23
    const int z = ntz >> 3;              // 0..2
    const int nt = ntz & 7;              // 0..7
    const int mt = s & 7;                // 0..7
    const int bm = (xcd * 8 + mt) * 128;
    const int bn = nt * 128;

    const u16* Bw = wt + (size_t)z * WSZE;

    f32x4 acc[4][4];
    gemm_nt_128(xh, Bw, bm, bn, lds, acc);

    const int lane = threadIdx.x & 63, wid = threadIdx.x >> 6;
    const int wm = wid >> 1, wn = wid & 1;
    const int lr = lane & 15, g = lane >> 4;

    if (z < 2) {
        const float scale = (z == 0) ? QSCALE : 1.0f;
        u16* outh = qkvb + (size_t)z * SZE;
#pragma unroll
        for (int fi = 0; fi < 4; ++fi)
#pragma unroll
            for (int fj = 0; fj < 4; ++fj)
#pragma unroll
                for (int reg = 0; reg < 4; ++reg) {
                    int m = bm + wm * 64 + fi * 16 + g * 4 + reg;
                    int n = bn + wn * 64 + fj * 16 + lr;
                    int b = m >> 11, t = m & (TB - 1);
                    int h = n >> 6, d = n & 63;
                    size_t o = ((size_t)(b * NH + h) * TB + t) * HD + d;
                    outh[o] = f2h(acc[fi][fj][reg] * scale);
                }
    } else {
        u16* vth = qkvb + (size_t)2 * SZE;
#pragma unroll
        for (int fi = 0; fi < 4; ++fi)
#pragma unroll
            for (int fj = 0; fj < 4; ++fj) {
                int n = bn + wn * 64 + fj * 16 + lr;
                int h = n >> 6, d = n & 63;
                int m0 = bm + wm * 64 + fi * 16 + g * 4;
                int b = m0 >> 11, t = m0 & (TB - 1);
                u16x4 v4;
#pragma unroll
                for (int reg = 0; reg < 4; ++reg) v4[reg] = f2h(acc[fi][fj][reg]);
                *(u16x4*)(vth + ((size_t)(b * NH + h) * HD + d) * TB + t) = v4;
            }
    }
}

// Output projection + bias -> fp32 out. XCD-aware 1-D grid (512 blocks).
__global__ __launch_bounds__(256) void proj_gemm(const u16* __restrict__ ch,
                                                 const u16* __restrict__ Bw,
                                                 const float* __restrict__ bo,
                                                 float* __restrict__ out)
{
    __shared__ u16 lds[8192];
    const int f = blockIdx.x;
    const int xcd = f & 7, s = f >> 3;   // 0..63
    const int nt = s >> 3, mt = s & 7;
    const int bm = (xcd * 8 + mt) * 128;
    const int bn = nt * 128;

    f32x4 acc[4][4];
    gemm_nt_128(ch, Bw, bm, bn, lds, acc);

    const int lane = threadIdx.x & 63, wid = threadIdx.x >> 6;
    const int wm = wid >> 1, wn = wid & 1;
    const int lr = lane & 15, g = lane >> 4;
#pragma unroll
    for (int fi = 0; fi < 4; ++fi)
#pragma unroll
        for (int fj = 0; fj < 4; ++fj) {
            int n = bn + wn * 64 + fj * 16 + lr;
            float bias = bo[n];
#pragma unroll
            for (int reg = 0; reg < 4; ++reg) {
                int m = bm + wm * 64 + fi * 16 + g * 4 + reg;
                out[(size_t)m * DM + n] = acc[fi][fj][reg] + bias;
            }
        }
}

// ---------------------------------------------------------------------------
// Flash attention, swapped-operand fp16 MFMA, uniform-work pairing:
// each block processes q-tiles (8+pp) then (7-pp) -> 34 K/V-tiles per block,
// exactly constant across all 512 blocks (2 per CU, no imbalance).
// S^T = mfma(K,Q) with sigma-permuted K rows; P stays in registers and feeds
// O^T = mfma(Vt, P^T) directly. K/V double-buffered LDS, 1 barrier/tile.
// ---------------------------------------------------------------------------
__device__ __forceinline__ void stage_tile(const u16* __restrict__ Kh,
                                           const u16* __restrict__ Vth,
                                           size_t bh, int k0, u16* dst, int tid)
{
    int r = tid >> 3, sl = tid & 7;
    int src = sl ^ PHI(r);
    size_t gk = (bh * TB + k0 + r) * HD + src * 8;
    gload16(Kh + gk, dst + tid * 8);
    size_t gv = (bh * HD + r) * TB + k0 + src * 8;
    gload16(Vth + gv, dst + 4096 + tid * 8);
}

__global__ __launch_bounds__(512, 4) void attn_kernel(const u16* __restrict__ Qh,
                                                      const u16* __restrict__ Kh,
                                                      const u16* __restrict__ Vth,
                                                      u16* __restrict__ ctxh)
{
    __shared__ u16 lds[16384]; // buf0: K@0 V@4096; buf1: K@8192 V@12288

    const int tid = threadIdx.x, lane = tid & 63, wid = tid >> 6;
    const int lr = lane & 15, g = lane >> 4;

    // XCD-aware decode: f&7 = XCD; each XCD owns 8 (b,h) with all q-tiles.
    const int f = blockIdx.x;
    const int xcd = f & 7, s = f >> 3;      // 0..63
    const int bh_idx = xcd * 8 + (s >> 3);  // 0..63
    const int pp = s & 7;                   // pair slot
    const int b = bh_idx >> 4, h = bh_idx & 15;
    const size_t bh = (size_t)(b * NH + h);

    for (int half = 0; half < 2; ++half) {
        const int qi = half ? (7 - pp) : (8 + pp); // heavy first, then light
        const int q0 = qi * QBLK;
        const int nt = 2 * qi + 2;
        const int wq0 = q0 + wid * 16;
        const int qrow = wq0 + lr; // this lane's q-row

        // hoisted Q fragments (pre-scaled by QSCALE*log2e)
        f16x8 qa[2];
        {
            size_t rowoff = (bh * TB + qrow) * HD;
#pragma unroll
            for (int ks = 0; ks < 2; ++ks)
                qa[ks] = *(const f16x8*)(Qh + rowoff + ks * 32 + g * 8);
        }

        f32x4 o[4];
#pragma unroll
        for (int i = 0; i < 4; ++i) o[i] = (f32x4)0.f;
        float mrun = -INFINITY, lrun = 0.f;

        if (half) __syncthreads(); // protect LDS from previous half's readers
        stage_tile(Kh, Vth, bh, 0, lds, tid);

        for (int kt = 0; kt < nt; ++kt) {
            __syncthreads(); // drains vmcnt -> buf[kt&1] ready; prev readers done
            if (kt + 1 < nt)
                stage_tile(Kh, Vth, bh, (kt + 1) * 64,
                           lds + ((kt + 1) & 1) * 8192, tid);

            const int k0 = kt * 64;
            if (k0 > wq0 + 15) continue; // wave fully masked

            u16* sK = lds + (kt & 1) * 8192;
            u16* sV = sK + 4096;

            // ---- S^T = K Q (sigma-permuted A rows) ----
            f32x4 sv[4];
            __builtin_amdgcn_s_setprio(1);
#pragma unroll
            for (int fj = 0; fj < 4; ++fj) {
                sv[fj] = (f32x4)0.f;
                int R = 32 * (fj >> 1) + 8 * (lr >> 2) + 4 * (fj & 1) + (lr & 3);
#pragma unroll
                for (int ks = 0; ks < 2; ++ks) {
                    int sl = (ks * 4 + g) ^ PHI(R);
                    f16x8 kb = *(const f16x8*)(sK + R * 64 + sl * 8);
                    sv[fj] = MFMA16(kb, qa[ks], sv[fj]);
                }
            }
            __builtin_amdgcn_s_setprio(0);

            // ---- causal mask (key index is static per lane) ----
            if ((k0 + 63) > wq0) {
#pragma unroll
                for (int fj = 0; fj < 4; ++fj)
#pragma unroll
                    for (int reg = 0; reg < 4; ++reg) {
                        int key = k0 + 32 * (fj >> 1) + 8 * g + 4 * (fj & 1) + reg;
                        if (key > qrow) sv[fj][reg] = -INFINITY;
                    }
            }

            // ---- online softmax: lane-local 16 + 2 shfl; defer-max ----
            float mloc = -INFINITY;
#pragma unroll
            for (int fj = 0; fj < 4; ++fj)
#pragma unroll
                for (int reg = 0; reg < 4; ++reg) mloc = fmaxf(mloc, sv[fj][reg]);
            mloc = fmaxf(mloc, __shfl_xor(mloc, 16));
            mloc = fmaxf(mloc, __shfl_xor(mloc, 32));

            if (mloc > mrun + DEFER_THR) {
                float scx = exp2f(mrun - mloc);
                lrun *= scx;
#pragma unroll
                for (int fd = 0; fd < 4; ++fd) o[fd] *= scx;
                mrun = mloc;
            }

            float p[4][4];
            float rs = 0.f;
#pragma unroll
            for (int fj = 0; fj < 4; ++fj)
#pragma unroll
                for (int reg = 0; reg < 4; ++reg) {
                    p[fj][reg] = exp2f(sv[fj][reg] - mrun);
                    rs += p[fj][reg];
                }
            rs += __shfl_xor(rs, 16);
            rs += __shfl_xor(rs, 32);
            lrun += rs;

            // ---- pack P -> PV B-fragments (lane-local, no LDS) ----
            union { f16x8 v8; fp16x2 v2[4]; } pb0, pb1;
            pb0.v2[0] = __builtin_amdgcn_cvt_pkrtz(p[0][0], p[0][1]);
            pb0.v2[1] = __builtin_amdgcn_cvt_pkrtz(p[0][2], p[0][3]);
            pb0.v2[2] = __builtin_amdgcn_cvt_pkrtz(p[1][0], p[1][1]);
            pb0.v2[3] = __builtin_amdgcn_cvt_pkrtz(p[1][2], p[1][3]);
            pb1.v2[0] = __builtin_amdgcn_cvt_pkrtz(p[2][0], p[2][1]);
            pb1.v2[1] = __builtin_amdgcn_cvt_pkrtz(p[2][2], p[2][3]);
            pb1.v2[2] = __builtin_amdgcn_cvt_pkrtz(p[3][0], p[3][1]);
            pb1.v2[3] = __builtin_amdgcn_cvt_pkrtz(p[3][2], p[3][3]);

            // ---- O^T += Vt P^T ----
            __builtin_amdgcn_s_setprio(1);
#pragma unroll
            for (int fd = 0; fd < 4; ++fd) {
                int Rv = fd * 16 + lr;
#pragma unroll
                for (int ks = 0; ks < 2; ++ks) {
                    int sl = (ks * 4 + g) ^ PHI(Rv);
                    f16x8 vb = *(const f16x8*)(sV + Rv * 64 + sl * 8);
                    o[fd] = MFMA16(vb, ks ? pb1.v8 : pb0.v8, o[fd]);
                }
            }
            __builtin_amdgcn_s_setprio(0);
        }

        // ---- epilogue: lane (g,lr) holds O[qrow][d = fd*16+4g+reg] ----
        float inv = 1.f / lrun;
#pragma unroll
        for (int fd = 0; fd < 4; ++fd) {
            u16x4 st;
#pragma unroll
            for (int reg = 0; reg < 4; ++reg) st[reg] = f2h(o[fd][reg] * inv);
            int d = fd * 16 + 4 * g;
            *(u16x4*)(ctxh + ((size_t)b * TB + qrow) * DM + h * HD + d) = st;
        }
    }
}

// ---------------------------------------------------------------------------
extern "C" void kernel_launch(void* const* d_in, const int* in_sizes, int n_in,
                              void* d_out, int out_size, void* d_ws, size_t ws_size,
                              hipStream_t stream)
{
    const float* x  = (const float*)d_in[0];
    const float* Wq = (const float*)d_in[1];
    const float* Wk = (const float*)d_in[2];
    const float* Wv = (const float*)d_in[3];
    const float* Wo = (const float*)d_in[4];
    const float* bo = (const float*)d_in[5];
    float* out = (float*)d_out;

    u16* w = (u16*)d_ws;
    u16* xh   = w;                       // dead after qkv_gemm
    u16* wt   = w + SZE;                 // 4 * WSZE
    u16* qkvb = w + SZE + 4 * WSZE;      // q, k, vt (3 SZE)
    u16* qh   = qkvb;
    u16* kh   = qkvb + SZE;
    u16* vth  = qkvb + 2 * SZE;
    u16* ctxh = xh;                      // alias x (dead by attn time)

    convert_x<<<dim3(4096), 256, 0, stream>>>(x, xh);
    convert_wt<<<dim3(16, 16, 4), 256, 0, stream>>>(Wq, Wk, Wv, Wo, wt);
    qkv_gemm<<<dim3(1536), 256, 0, stream>>>(xh, wt, qkvb);
    attn_kernel<<<dim3(512), 512, 0, stream>>>(qh, kh, vth, ctxh);
    proj_gemm<<<dim3(512), 256, 0, stream>>>(ctxh, wt + 3 * WSZE, bo, out);
}